// Round 14
// baseline (299.924 us; speedup 1.0000x reference)
//
#include <hip/hip_runtime.h>
#include <hip/hip_fp16.h>

#define EPSF 1e-8f

typedef _Float16 half8 __attribute__((ext_vector_type(8)));
typedef float f32x4 __attribute__((ext_vector_type(4)));

// B=16, L=4096, I=64, H=512, O=1. M = B*L = 65536. CHUNK=64, NC=64.

__device__ __forceinline__ float sigmoidf_(float x) {
    return 1.0f / (1.0f + __expf(-x));
}
__device__ __forceinline__ float tanh_fast(float x) {  // x in (0,1)
    float e = __expf(-2.0f * x);
    return (1.0f - e) / (1.0f + e);
}
// transform pre-activations -> (a, b) of recurrence h = a*h + b
__device__ __forceinline__ void gate_transform(float pz, float ph, float& a, float& b) {
    float k = sigmoidf_(pz);          // k = sigmoid(x@Wz+bz)
    float z = sigmoidf_(k);           // z = sigmoid(k)   (faithful double-sigmoid)
    a = 1.0f - z;                     // exp(-softplus(k))
    float hw = tanh_fast(sigmoidf_(ph)) + EPSF;  // log_g(sigmoid(x@Wh+bh))
    b = z * hw;
}

// async global->LDS, 16B per lane; LDS dest = wave-uniform base + lane*16
__device__ __forceinline__ void gload16(const void* g, void* l) {
    __builtin_amdgcn_global_load_lds(
        (const __attribute__((address_space(1))) unsigned int*)g,
        (__attribute__((address_space(3))) unsigned int*)l, 16, 0, 0);
}

// Ordered affine compose across the 4 q-subgroups of a 64-lane wave.
__device__ __forceinline__ void qscan(int q, float pA, float pB,
                                      float& fA, float& fB, float& prA, float& prB)
{
    float oA = __shfl_xor(pA, 16, 64), oB = __shfl_xor(pB, 16, 64);
    float eA = (q & 1) ? oA : pA, eB = (q & 1) ? oB : pB;   // earlier of pair
    float lA = (q & 1) ? pA : oA, lB = (q & 1) ? pB : oB;   // later of pair
    float p2A = eA * lA;
    float p2B = fmaf(lA, eB, lB);
    float o2A = __shfl_xor(p2A, 32, 64), o2B = __shfl_xor(p2B, 32, 64);
    float loA = (q & 2) ? o2A : p2A, loB = (q & 2) ? o2B : p2B;
    float hiA = (q & 2) ? p2A : o2A, hiB = (q & 2) ? p2B : o2B;
    fA = loA * hiA;
    fB = fmaf(hiA, loB, hiB);
    prA = (q & 2) ? o2A : 1.0f;
    prB = (q & 2) ? o2B : 0.0f;
    if (q & 1) { prB = fmaf(oA, prB, oB); prA *= oA; }
}

// ---------------- kprep: x f32->fp16 (blocks 0..2047) + 4 weight transposes ------
__global__ __launch_bounds__(256) void kprep(
    const float* __restrict__ x, __half* __restrict__ x16,
    const float* __restrict__ Wz1, const float* __restrict__ Wh1,
    __half* __restrict__ Wtz1, __half* __restrict__ Wth1,
    const float* __restrict__ Wz0, const float* __restrict__ Wh0,
    __half* __restrict__ Wtz0, __half* __restrict__ Wth0)
{
    __shared__ float t[64][65];
    const int tid = threadIdx.x;
    int b = blockIdx.x;
    if (b < 2048) {
        const size_t i = ((size_t)(b * 256 + tid)) * 8;
        float4 v0 = *(const float4*)&x[i];
        float4 v1 = *(const float4*)&x[i + 4];
        __half2* o = (__half2*)(x16 + i);
        o[0] = __floats2half2_rn(v0.x, v0.y);
        o[1] = __floats2half2_rn(v0.z, v0.w);
        o[2] = __floats2half2_rn(v1.x, v1.y);
        o[3] = __floats2half2_rn(v1.z, v1.w);
        return;
    }
    b -= 2048;
    const float* W; __half* Wt; int ldt, n0, k0;
    if (b < 64)       { W = Wz1; Wt = Wtz1; ldt = 512; n0 = (b & 7) * 64; k0 = (b >> 3) * 64; }
    else if (b < 128) { b -= 64;  W = Wh1; Wt = Wth1; ldt = 512; n0 = (b & 7) * 64; k0 = (b >> 3) * 64; }
    else if (b < 136) { b -= 128; W = Wz0; Wt = Wtz0; ldt = 64;  n0 = b * 64; k0 = 0; }
    else              { b -= 136; W = Wh0; Wt = Wth0; ldt = 64;  n0 = b * 64; k0 = 0; }
    const int r = tid >> 4, c4 = (tid & 15) * 4;
#pragma unroll
    for (int rr = 0; rr < 64; rr += 16)
        *(float4*)&t[rr + r][c4] = *(const float4*)&W[(size_t)(k0 + rr + r) * 512 + n0 + c4];
    __syncthreads();
#pragma unroll
    for (int rr = 0; rr < 64; rr += 16) {
        const int row = rr + r;
        __half2 h01 = __floats2half2_rn(t[c4 + 0][row], t[c4 + 1][row]);
        __half2 h23 = __floats2half2_rn(t[c4 + 2][row], t[c4 + 3][row]);
        *(__half2*)&Wt[(size_t)(n0 + row) * ldt + k0 + c4] = h01;
        *(__half2*)&Wt[(size_t)(n0 + row) * ldt + k0 + c4 + 2] = h23;
    }
}

// ---------------- k1: layer-0 MFMA GEMM (K=64), BM=128 x BN=64 -------------------
// MODE 0: transform + chunk summaries -> sumA/sumB
// MODE 1: transform + in-register chunk scan with carry-in -> h0 via LDS transpose
// Block 256 thr (4 waves, 2m x 2n), wave tile 64m x 32n x {z,h}. Grid (8, 512).
template<int MODE>
__global__ __launch_bounds__(256) void k1_l0(
    const __half* __restrict__ x16,
    const __half* __restrict__ Wtz, const __half* __restrict__ Wth,  // [512][64] fp16
    const float* __restrict__ bz, const float* __restrict__ bh,
    float* __restrict__ sumA, float* __restrict__ sumB,
    const float* __restrict__ carry, __half* __restrict__ h0)
{
    __shared__ char smem1[32768];
    __half* As = (__half*)smem1;       // [128 rows][64 k] swizzled (16 KB)
    __half* Bs = As + 128 * 64;        // [128 rows][64 k]: rows<64 z, >=64 h (16 KB)
    const int tid = threadIdx.x;
    const int wave = tid >> 6, lane = tid & 63;
    const int q = lane >> 4, l16 = lane & 15;
    const int wm = wave >> 1, wn = wave & 1;

    const int Lb = blockIdx.x + 8 * blockIdx.y;          // 0..4095
    const int lin = (Lb & 7) * 512 + (Lb >> 3);          // bijective XCD swizzle
    const int bx = lin & 7, by = lin >> 3;
    const int m0 = by * 128, n0 = bx * 64;

    {   // stage A (16 regions x 1KB) + B (16 regions); 128B rows, 8 chunks, swz ^(row&7)
        const int r8 = lane >> 3, ch = lane & 7;
#pragma unroll
        for (int i = 0; i < 4; ++i) {
            const int reg = wave * 4 + i;
            const int row = reg * 8 + r8;
            gload16(x16 + (size_t)(m0 + row) * 64 + ((ch ^ (row & 7)) << 3),
                    (char*)As + reg * 1024);
        }
#pragma unroll
        for (int i = 0; i < 4; ++i) {
            const int reg = wave * 4 + i;
            const int row = reg * 8 + r8;
            const __half* src = (row < 64) ? (Wtz + (size_t)(n0 + row) * 64)
                                           : (Wth + (size_t)(n0 + row - 64) * 64);
            gload16(src + ((ch ^ (row & 7)) << 3), (char*)Bs + reg * 1024);
        }
    }
    __syncthreads();

    f32x4 accz[4][2], acch[4][2];
#pragma unroll
    for (int mi = 0; mi < 4; ++mi)
#pragma unroll
        for (int ni = 0; ni < 2; ++ni) {
            accz[mi][ni] = (f32x4){0.f, 0.f, 0.f, 0.f};
            acch[mi][ni] = (f32x4){0.f, 0.f, 0.f, 0.f};
        }

#pragma unroll
    for (int s = 0; s < 2; ++s) {
        half8 af[4];
#pragma unroll
        for (int mi = 0; mi < 4; ++mi) {
            const int row = wm * 64 + mi * 16 + l16;
            const int pc = (s * 4 + q) ^ (row & 7);
            af[mi] = *(const half8*)&As[row * 64 + pc * 8];
        }
#pragma unroll
        for (int ni = 0; ni < 2; ++ni) {
            const int rn = wn * 32 + ni * 16 + l16;           // 0..63
            const int pc = (s * 4 + q) ^ (rn & 7);
            half8 bzf = *(const half8*)&Bs[rn * 64 + pc * 8];
            half8 bhf = *(const half8*)&Bs[(64 + rn) * 64 + pc * 8];
#pragma unroll
            for (int mi = 0; mi < 4; ++mi) {
                accz[mi][ni] = __builtin_amdgcn_mfma_f32_16x16x32_f16(af[mi], bzf, accz[mi][ni], 0, 0, 0);
                acch[mi][ni] = __builtin_amdgcn_mfma_f32_16x16x32_f16(af[mi], bhf, acch[mi][ni], 0, 0, 0);
            }
        }
    }

    // epilogue. C layout: row(m) = q*4 + j (+mi*16), col(n) = l16 (+ni*16)
    const int bidx = by >> 5;                    // 32 m-tiles per batch
    const int chunkg = ((by & 31) << 1) + wm;
    const size_t srow = ((size_t)(bidx * 64 + chunkg)) << 9;

    if (MODE == 1) __syncthreads();    // done reading As/Bs -> overlay h0s
    __half* h0s = (__half*)smem1;      // [128][68] fp16, 17408 B

#pragma unroll
    for (int ni = 0; ni < 2; ++ni) {
        const int colloc = wn * 32 + ni * 16 + l16;           // 0..63
        const int col = n0 + colloc;
        const float bzv = bz[col], bhv = bh[col];
        if (MODE == 0) {
            float fullA = 1.f, fullB = 0.f;
#pragma unroll
            for (int mi = 0; mi < 4; ++mi) {
                float pA = 1.f, pB = 0.f;
#pragma unroll
                for (int j = 0; j < 4; ++j) {
                    float a, b;
                    gate_transform(accz[mi][ni][j] + bzv, acch[mi][ni][j] + bhv, a, b);
                    pB = fmaf(a, pB, b); pA *= a;
                }
                float fA, fB, prA, prB;
                qscan(q, pA, pB, fA, fB, prA, prB);
                fullB = fmaf(fA, fullB, fB); fullA *= fA;
            }
            if (q == 0) { sumA[srow + col] = fullA; sumB[srow + col] = fullB; }
        } else {
            float H = carry[srow + col];
#pragma unroll
            for (int mi = 0; mi < 4; ++mi) {
                float av[4], bv[4];
                float pA = 1.f, pB = 0.f;
#pragma unroll
                for (int j = 0; j < 4; ++j) {
                    gate_transform(accz[mi][ni][j] + bzv, acch[mi][ni][j] + bhv, av[j], bv[j]);
                    pB = fmaf(av[j], pB, bv[j]); pA *= av[j];
                }
                float fA, fB, prA, prB;
                qscan(q, pA, pB, fA, fB, prA, prB);
                float Hl = fmaf(prA, H, prB);        // h before this lane's 4 rows
                const int rloc = wm * 64 + mi * 16 + q * 4;
#pragma unroll
                for (int j = 0; j < 4; ++j) {
                    Hl = fmaf(av[j], Hl, bv[j]);
                    h0s[(rloc + j) * 68 + colloc] = (__half)Hl;
                }
                H = fmaf(fA, H, fB);
            }
        }
    }
    if (MODE == 1) {
        __syncthreads();
        const int row = tid >> 1, cpart = tid & 1;
        const __half* srcp = h0s + row * 68 + cpart * 32;
        __half* dstp = h0 + (size_t)(m0 + row) * 512 + n0 + cpart * 32;
#pragma unroll
        for (int i = 0; i < 4; ++i)
            *(uint4*)(dstp + i * 8) = *(const uint4*)(srcp + i * 8);
    }
}

// ---------------- k2: scan chunk summaries -> per-chunk carry-in ------------------
__global__ __launch_bounds__(256) void k2_carry(
    const float* __restrict__ sumA, const float* __restrict__ sumB,
    float* __restrict__ carry)
{
    const int idx = blockIdx.x * 256 + threadIdx.x;  // 0..8191
    const int b = idx >> 9, h = idx & 511;
    const size_t base = (((size_t)b * 64) << 9) + h;
    float H = EPSF;
#pragma unroll
    for (int c = 0; c < 64; c += 8) {
        float av[8], bv[8];
#pragma unroll
        for (int u = 0; u < 8; ++u) {           // independent loads issue together
            const size_t o = base + ((size_t)(c + u) << 9);
            av[u] = sumA[o]; bv[u] = sumB[o];
        }
#pragma unroll
        for (int u = 0; u < 8; ++u) {
            carry[base + ((size_t)(c + u) << 9)] = H;
            H = fmaf(av[u], H, bv[u]);
        }
    }
}

// ---------------- k4: layer-1 MFMA GEMM (K=512) + transform + chunk summaries -----
// r13 structure (counted vmcnt(6) + raw barriers + (256,2) clamp) with the
// per-iteration address VALU removed: main loop FULLY UNROLLED, 6 global source
// pointers hoisted (K-walk = compile-time immediate offsets), 6 wave-uniform LDS
// dests, 12 per-lane ds_read byte offsets computed once (buffer alternation =
// compile-time base + offset immediates).
// Block 256 thr (4 waves, 2m x 2n), tile 128m x 128n, K_STEP 32, dbuf, grid (4,512).
__global__ __launch_bounds__(256, 2) void k4_l1(
    const __half* __restrict__ h0,
    const __half* __restrict__ Wtz, const __half* __restrict__ Wth,  // [512][512] fp16
    const float* __restrict__ bz, const float* __restrict__ bh,
    float* __restrict__ sumA, float* __restrict__ sumB)
{
    __shared__ char smem4[2][24576];     // per buf: A 8KB (128x32) + B 16KB (256x32)
    const int tid = threadIdx.x;
    const int wave = tid >> 6, lane = tid & 63;
    const int q = lane >> 4, l16 = lane & 15;
    const int wm = wave >> 1, wn = wave & 1;

    const int Lb = blockIdx.x + 4 * blockIdx.y;
    const int lin = (Lb & 7) * 256 + (Lb >> 3);
    const int bx = lin & 3, by = lin >> 2;
    const int m0 = by * 128, n0 = bx * 128;

    const int r4 = lane >> 2, ch = lane & 3;

    // hoisted staging sources (per-lane) + LDS dest byte offsets (wave-uniform)
    const __half* aSrc[2]; int aDst[2];
#pragma unroll
    for (int i = 0; i < 2; ++i) {
        const int reg = wave * 2 + i;
        const int row = reg * 16 + r4;
        const int pc = ch ^ ((row >> 1) & 3);
        aSrc[i] = h0 + (size_t)(m0 + row) * 512 + pc * 8;
        aDst[i] = reg * 1024;                         // within A region
    }
    const __half* bSrc[4]; int bDst[4];
#pragma unroll
    for (int i = 0; i < 4; ++i) {
        const int reg = wave * 4 + i;
        const int row = reg * 16 + r4;
        const int pc = ch ^ ((row >> 1) & 3);
        bSrc[i] = ((row < 128) ? (Wtz + (size_t)(n0 + row) * 512)
                               : (Wth + (size_t)(n0 + row - 128) * 512)) + pc * 8;
        bDst[i] = 8192 + reg * 1024;                  // B region starts at 8KB
    }
    // hoisted ds_read byte offsets (within one buffer)
    int aOff[4], bOff[4];
#pragma unroll
    for (int mi = 0; mi < 4; ++mi) {
        const int row = wm * 64 + mi * 16 + l16;
        aOff[mi] = row * 64 + ((q ^ ((row >> 1) & 3)) << 4);
    }
#pragma unroll
    for (int ni = 0; ni < 4; ++ni) {
        const int rn = wn * 64 + ni * 16 + l16;
        bOff[ni] = 8192 + rn * 64 + ((q ^ ((rn >> 1) & 3)) << 4);
    }

    f32x4 accz[4][4], acch[4][4];
#pragma unroll
    for (int mi = 0; mi < 4; ++mi)
#pragma unroll
        for (int ni = 0; ni < 4; ++ni) {
            accz[mi][ni] = (f32x4){0.f, 0.f, 0.f, 0.f};
            acch[mi][ni] = (f32x4){0.f, 0.f, 0.f, 0.f};
        }

    auto stage = [&](int c, int t) {     // 6 gload16; t compile-time under unroll
#pragma unroll
        for (int i = 0; i < 2; ++i)
            gload16(aSrc[i] + t * 32, smem4[c] + aDst[i]);
#pragma unroll
        for (int i = 0; i < 4; ++i)
            gload16(bSrc[i] + t * 32, smem4[c] + bDst[i]);
    };
    auto compute = [&](int c) {
        half8 af[4];
#pragma unroll
        for (int mi = 0; mi < 4; ++mi)
            af[mi] = *(const half8*)(smem4[c] + aOff[mi]);
        __builtin_amdgcn_s_setprio(1);
#pragma unroll
        for (int ni = 0; ni < 4; ++ni) {
            half8 bzf = *(const half8*)(smem4[c] + bOff[ni]);
            half8 bhf = *(const half8*)(smem4[c] + 8192 + bOff[ni]);
#pragma unroll
            for (int mi = 0; mi < 4; ++mi) {
                accz[mi][ni] = __builtin_amdgcn_mfma_f32_16x16x32_f16(af[mi], bzf, accz[mi][ni], 0, 0, 0);
                acch[mi][ni] = __builtin_amdgcn_mfma_f32_16x16x32_f16(af[mi], bhf, acch[mi][ni], 0, 0, 0);
            }
        }
        __builtin_amdgcn_s_setprio(0);
    };

    stage(0, 0);
#pragma unroll
    for (int t = 0; t < 15; ++t) {             // fully unrolled steady state
        const int c = t & 1;
        stage(c ^ 1, t + 1);                   // issue next tile (6 loads in flight)
        asm volatile("s_waitcnt vmcnt(6)" ::: "memory");   // tile t landed
        __builtin_amdgcn_s_barrier();          // tile t visible to all waves
        compute(c);
        __builtin_amdgcn_s_barrier();          // reads of buf c done (no drain)
    }
    asm volatile("s_waitcnt vmcnt(0)" ::: "memory");       // drain tile 15
    __builtin_amdgcn_s_barrier();
    compute(1);

    // epilogue: transform + chunk summary (wave wm owns chunk)
    const int bidx = by >> 5;
    const int chunkg = ((by & 31) << 1) + wm;
    const size_t srow = ((size_t)(bidx * 64 + chunkg)) << 9;
#pragma unroll
    for (int ni = 0; ni < 4; ++ni) {
        const int col = n0 + wn * 64 + ni * 16 + l16;
        const float bzv = bz[col], bhv = bh[col];
        float fullA = 1.f, fullB = 0.f;
#pragma unroll
        for (int mi = 0; mi < 4; ++mi) {
            float pA = 1.f, pB = 0.f;
#pragma unroll
            for (int j = 0; j < 4; ++j) {
                float a, b;
                gate_transform(accz[mi][ni][j] + bzv, acch[mi][ni][j] + bhv, a, b);
                pB = fmaf(a, pB, b); pA *= a;
            }
            float fA, fB, prA, prB;
            qscan(q, pA, pB, fA, fB, prA, prB);
            fullB = fmaf(fA, fullB, fB); fullA *= fA;
        }
        if (q == 0) { sumA[srow + col] = fullA; sumB[srow + col] = fullB; }
    }
}

// ---------------- k5: final chunk scan + GEMV with Wf ----------------------------
__global__ __launch_bounds__(512) void k5_final(
    const float* __restrict__ sumA, const float* __restrict__ sumB,
    const float* __restrict__ Wf, const float* __restrict__ bf,
    float* __restrict__ out)
{
    const int b = blockIdx.x, h = threadIdx.x;
    const size_t base = (((size_t)b * 64) << 9) + h;
    float H = EPSF;
#pragma unroll
    for (int c = 0; c < 64; c += 8) {
        float av[8], bv[8];
#pragma unroll
        for (int u = 0; u < 8; ++u) {
            const size_t o = base + ((size_t)(c + u) << 9);
            av[u] = sumA[o]; bv[u] = sumB[o];
        }
#pragma unroll
        for (int u = 0; u < 8; ++u) H = fmaf(av[u], H, bv[u]);
    }
    float v = H * Wf[h];
#pragma unroll
    for (int off = 32; off; off >>= 1) v += __shfl_down(v, off, 64);
    __shared__ float wsum[8];
    if ((h & 63) == 0) wsum[h >> 6] = v;
    __syncthreads();
    if (h == 0) {
        float s = 0.f;
#pragma unroll
        for (int i = 0; i < 8; ++i) s += wsum[i];
        out[b] = s + bf[0];
    }
}

extern "C" void kernel_launch(void* const* d_in, const int* in_sizes, int n_in,
                              void* d_out, int out_size, void* d_ws, size_t ws_size,
                              hipStream_t stream)
{
    const float* x   = (const float*)d_in[0];
    const float* Wz0 = (const float*)d_in[1];
    const float* bz0 = (const float*)d_in[2];
    const float* Wh0 = (const float*)d_in[3];
    const float* bh0 = (const float*)d_in[4];
    const float* Wz1 = (const float*)d_in[5];
    const float* bz1 = (const float*)d_in[6];
    const float* Wh1 = (const float*)d_in[7];
    const float* bh1 = (const float*)d_in[8];
    const float* Wf  = (const float*)d_in[9];
    const float* bf  = (const float*)d_in[10];
    float* out = (float*)d_out;

    // workspace layout (~80 MiB)
    char* ws = (char*)d_ws;
    __half* x16  = (__half*)ws;                          // 8 MiB
    __half* h0b  = (__half*)(ws + ((size_t)8 << 20));    // 64 MiB
    __half* Wtz1 = (__half*)(ws + ((size_t)72 << 20));   // 512 KiB
    __half* Wth1 = Wtz1 + 262144;                        // 512 KiB
    __half* Wtz0 = Wth1 + 262144;                        // 64 KiB
    __half* Wth0 = Wtz0 + 32768;                         // 64 KiB
    float* sumA  = (float*)(ws + ((size_t)74 << 20));    // 2 MiB
    float* sumB  = sumA + 524288;                        // 2 MiB
    float* carry = sumB + 524288;                        // 2 MiB

    kprep<<<2192, 256, 0, stream>>>(x, x16, Wz1, Wh1, Wtz1, Wth1,
                                    Wz0, Wh0, Wtz0, Wth0);
    k1_l0<0><<<dim3(8, 512), 256, 0, stream>>>(x16, Wtz0, Wth0, bz0, bh0,
                                               sumA, sumB, nullptr, nullptr);
    k2_carry<<<32, 256, 0, stream>>>(sumA, sumB, carry);
    k1_l0<1><<<dim3(8, 512), 256, 0, stream>>>(x16, Wtz0, Wth0, bz0, bh0,
                                               nullptr, nullptr, carry, h0b);
    k4_l1<<<dim3(4, 512), 256, 0, stream>>>(h0b, Wtz1, Wth1, bz1, bh1, sumA, sumB);
    k5_final<<<16, 512, 0, stream>>>(sumA, sumB, Wf, bf, out);
}

// Round 15
// 203.412 us; speedup vs baseline: 1.4745x; 1.4745x over previous
//
#include <hip/hip_runtime.h>
#include <hip/hip_fp16.h>

#define EPSF 1e-8f

typedef _Float16 half8 __attribute__((ext_vector_type(8)));
typedef float f32x4 __attribute__((ext_vector_type(4)));

// B=16, L=4096, I=64, H=512, O=1. M = B*L = 65536. CHUNK=64, NC=64.

__device__ __forceinline__ float fast_rcp(float x) {
    return __builtin_amdgcn_rcpf(x);   // v_rcp_f32, ~1 ulp
}
// transform pre-activations -> (a, b) of recurrence h = a*h + b
// division-free: sigma(x) = rcp(1+exp(-x)); 1-sigma(k) = ek*z exactly.
__device__ __forceinline__ void gate_transform(float pz, float ph, float& a, float& b) {
    float ez = __expf(-pz);
    float k  = fast_rcp(1.0f + ez);          // k = sigmoid(pz)
    float ek = __expf(-k);
    float z  = fast_rcp(1.0f + ek);          // z = sigmoid(k)
    a = ek * z;                              // a = 1 - z (exact algebra)
    float es = __expf(-ph);
    float s  = fast_rcp(1.0f + es);          // sigmoid(ph)
    float e2 = __expf(-2.0f * s);
    float hw = (1.0f - e2) * fast_rcp(1.0f + e2) + EPSF;  // tanh(s)+eps
    b = z * hw;
}

// async global->LDS, 16B per lane; LDS dest = wave-uniform base + lane*16
__device__ __forceinline__ void gload16(const void* g, void* l) {
    __builtin_amdgcn_global_load_lds(
        (const __attribute__((address_space(1))) unsigned int*)g,
        (__attribute__((address_space(3))) unsigned int*)l, 16, 0, 0);
}

// Ordered affine compose across the 4 q-subgroups of a 64-lane wave.
__device__ __forceinline__ void qscan(int q, float pA, float pB,
                                      float& fA, float& fB, float& prA, float& prB)
{
    float oA = __shfl_xor(pA, 16, 64), oB = __shfl_xor(pB, 16, 64);
    float eA = (q & 1) ? oA : pA, eB = (q & 1) ? oB : pB;   // earlier of pair
    float lA = (q & 1) ? pA : oA, lB = (q & 1) ? pB : oB;   // later of pair
    float p2A = eA * lA;
    float p2B = fmaf(lA, eB, lB);
    float o2A = __shfl_xor(p2A, 32, 64), o2B = __shfl_xor(p2B, 32, 64);
    float loA = (q & 2) ? o2A : p2A, loB = (q & 2) ? o2B : p2B;
    float hiA = (q & 2) ? p2A : o2A, hiB = (q & 2) ? p2B : o2B;
    fA = loA * hiA;
    fB = fmaf(hiA, loB, hiB);
    prA = (q & 2) ? o2A : 1.0f;
    prB = (q & 2) ? o2B : 0.0f;
    if (q & 1) { prB = fmaf(oA, prB, oB); prA *= oA; }
}

// ---------------- kprep: x f32->fp16 (blocks 0..2047) + 4 weight transposes ------
__global__ __launch_bounds__(256) void kprep(
    const float* __restrict__ x, __half* __restrict__ x16,
    const float* __restrict__ Wz1, const float* __restrict__ Wh1,
    __half* __restrict__ Wtz1, __half* __restrict__ Wth1,
    const float* __restrict__ Wz0, const float* __restrict__ Wh0,
    __half* __restrict__ Wtz0, __half* __restrict__ Wth0)
{
    __shared__ float t[64][65];
    const int tid = threadIdx.x;
    int b = blockIdx.x;
    if (b < 2048) {
        const size_t i = ((size_t)(b * 256 + tid)) * 8;
        float4 v0 = *(const float4*)&x[i];
        float4 v1 = *(const float4*)&x[i + 4];
        __half2* o = (__half2*)(x16 + i);
        o[0] = __floats2half2_rn(v0.x, v0.y);
        o[1] = __floats2half2_rn(v0.z, v0.w);
        o[2] = __floats2half2_rn(v1.x, v1.y);
        o[3] = __floats2half2_rn(v1.z, v1.w);
        return;
    }
    b -= 2048;
    const float* W; __half* Wt; int ldt, n0, k0;
    if (b < 64)       { W = Wz1; Wt = Wtz1; ldt = 512; n0 = (b & 7) * 64; k0 = (b >> 3) * 64; }
    else if (b < 128) { b -= 64;  W = Wh1; Wt = Wth1; ldt = 512; n0 = (b & 7) * 64; k0 = (b >> 3) * 64; }
    else if (b < 136) { b -= 128; W = Wz0; Wt = Wtz0; ldt = 64;  n0 = b * 64; k0 = 0; }
    else              { b -= 136; W = Wh0; Wt = Wth0; ldt = 64;  n0 = b * 64; k0 = 0; }
    const int r = tid >> 4, c4 = (tid & 15) * 4;
#pragma unroll
    for (int rr = 0; rr < 64; rr += 16)
        *(float4*)&t[rr + r][c4] = *(const float4*)&W[(size_t)(k0 + rr + r) * 512 + n0 + c4];
    __syncthreads();
#pragma unroll
    for (int rr = 0; rr < 64; rr += 16) {
        const int row = rr + r;
        __half2 h01 = __floats2half2_rn(t[c4 + 0][row], t[c4 + 1][row]);
        __half2 h23 = __floats2half2_rn(t[c4 + 2][row], t[c4 + 3][row]);
        *(__half2*)&Wt[(size_t)(n0 + row) * ldt + k0 + c4] = h01;
        *(__half2*)&Wt[(size_t)(n0 + row) * ldt + k0 + c4 + 2] = h23;
    }
}

// ---------------- k1: layer-0 MFMA GEMM (K=64), BM=128 x BN=64 -------------------
// MODE 0: transform + chunk summaries -> sumA/sumB
// MODE 1: transform + in-register chunk scan with carry-in -> h0 via LDS transpose
// Block 256 thr (4 waves, 2m x 2n), wave tile 64m x 32n x {z,h}. Grid (8, 512).
template<int MODE>
__global__ __launch_bounds__(256) void k1_l0(
    const __half* __restrict__ x16,
    const __half* __restrict__ Wtz, const __half* __restrict__ Wth,  // [512][64] fp16
    const float* __restrict__ bz, const float* __restrict__ bh,
    float* __restrict__ sumA, float* __restrict__ sumB,
    const float* __restrict__ carry, __half* __restrict__ h0)
{
    __shared__ char smem1[32768];
    __half* As = (__half*)smem1;       // [128 rows][64 k] swizzled (16 KB)
    __half* Bs = As + 128 * 64;        // [128 rows][64 k]: rows<64 z, >=64 h (16 KB)
    const int tid = threadIdx.x;
    const int wave = tid >> 6, lane = tid & 63;
    const int q = lane >> 4, l16 = lane & 15;
    const int wm = wave >> 1, wn = wave & 1;

    const int Lb = blockIdx.x + 8 * blockIdx.y;          // 0..4095
    const int lin = (Lb & 7) * 512 + (Lb >> 3);          // bijective XCD swizzle
    const int bx = lin & 7, by = lin >> 3;
    const int m0 = by * 128, n0 = bx * 64;

    {   // stage A (16 regions x 1KB) + B (16 regions); 128B rows, 8 chunks, swz ^(row&7)
        const int r8 = lane >> 3, ch = lane & 7;
#pragma unroll
        for (int i = 0; i < 4; ++i) {
            const int reg = wave * 4 + i;
            const int row = reg * 8 + r8;
            gload16(x16 + (size_t)(m0 + row) * 64 + ((ch ^ (row & 7)) << 3),
                    (char*)As + reg * 1024);
        }
#pragma unroll
        for (int i = 0; i < 4; ++i) {
            const int reg = wave * 4 + i;
            const int row = reg * 8 + r8;
            const __half* src = (row < 64) ? (Wtz + (size_t)(n0 + row) * 64)
                                           : (Wth + (size_t)(n0 + row - 64) * 64);
            gload16(src + ((ch ^ (row & 7)) << 3), (char*)Bs + reg * 1024);
        }
    }
    __syncthreads();

    f32x4 accz[4][2], acch[4][2];
#pragma unroll
    for (int mi = 0; mi < 4; ++mi)
#pragma unroll
        for (int ni = 0; ni < 2; ++ni) {
            accz[mi][ni] = (f32x4){0.f, 0.f, 0.f, 0.f};
            acch[mi][ni] = (f32x4){0.f, 0.f, 0.f, 0.f};
        }

#pragma unroll
    for (int s = 0; s < 2; ++s) {
        half8 af[4];
#pragma unroll
        for (int mi = 0; mi < 4; ++mi) {
            const int row = wm * 64 + mi * 16 + l16;
            const int pc = (s * 4 + q) ^ (row & 7);
            af[mi] = *(const half8*)&As[row * 64 + pc * 8];
        }
#pragma unroll
        for (int ni = 0; ni < 2; ++ni) {
            const int rn = wn * 32 + ni * 16 + l16;           // 0..63
            const int pc = (s * 4 + q) ^ (rn & 7);
            half8 bzf = *(const half8*)&Bs[rn * 64 + pc * 8];
            half8 bhf = *(const half8*)&Bs[(64 + rn) * 64 + pc * 8];
#pragma unroll
            for (int mi = 0; mi < 4; ++mi) {
                accz[mi][ni] = __builtin_amdgcn_mfma_f32_16x16x32_f16(af[mi], bzf, accz[mi][ni], 0, 0, 0);
                acch[mi][ni] = __builtin_amdgcn_mfma_f32_16x16x32_f16(af[mi], bhf, acch[mi][ni], 0, 0, 0);
            }
        }
    }

    // epilogue. C layout: row(m) = q*4 + j (+mi*16), col(n) = l16 (+ni*16)
    const int bidx = by >> 5;                    // 32 m-tiles per batch
    const int chunkg = ((by & 31) << 1) + wm;
    const size_t srow = ((size_t)(bidx * 64 + chunkg)) << 9;

    if (MODE == 1) __syncthreads();    // done reading As/Bs -> overlay h0s
    __half* h0s = (__half*)smem1;      // [128][68] fp16, 17408 B

#pragma unroll
    for (int ni = 0; ni < 2; ++ni) {
        const int colloc = wn * 32 + ni * 16 + l16;           // 0..63
        const int col = n0 + colloc;
        const float bzv = bz[col], bhv = bh[col];
        if (MODE == 0) {
            float fullA = 1.f, fullB = 0.f;
#pragma unroll
            for (int mi = 0; mi < 4; ++mi) {
                float pA = 1.f, pB = 0.f;
#pragma unroll
                for (int j = 0; j < 4; ++j) {
                    float a, b;
                    gate_transform(accz[mi][ni][j] + bzv, acch[mi][ni][j] + bhv, a, b);
                    pB = fmaf(a, pB, b); pA *= a;
                }
                float fA, fB, prA, prB;
                qscan(q, pA, pB, fA, fB, prA, prB);
                fullB = fmaf(fA, fullB, fB); fullA *= fA;
            }
            if (q == 0) { sumA[srow + col] = fullA; sumB[srow + col] = fullB; }
        } else {
            float H = carry[srow + col];
#pragma unroll
            for (int mi = 0; mi < 4; ++mi) {
                float av[4], bv[4];
                float pA = 1.f, pB = 0.f;
#pragma unroll
                for (int j = 0; j < 4; ++j) {
                    gate_transform(accz[mi][ni][j] + bzv, acch[mi][ni][j] + bhv, av[j], bv[j]);
                    pB = fmaf(av[j], pB, bv[j]); pA *= av[j];
                }
                float fA, fB, prA, prB;
                qscan(q, pA, pB, fA, fB, prA, prB);
                float Hl = fmaf(prA, H, prB);        // h before this lane's 4 rows
                const int rloc = wm * 64 + mi * 16 + q * 4;
#pragma unroll
                for (int j = 0; j < 4; ++j) {
                    Hl = fmaf(av[j], Hl, bv[j]);
                    h0s[(rloc + j) * 68 + colloc] = (__half)Hl;
                }
                H = fmaf(fA, H, fB);
            }
        }
    }
    if (MODE == 1) {
        __syncthreads();
        const int row = tid >> 1, cpart = tid & 1;
        const __half* srcp = h0s + row * 68 + cpart * 32;
        __half* dstp = h0 + (size_t)(m0 + row) * 512 + n0 + cpart * 32;
#pragma unroll
        for (int i = 0; i < 4; ++i)
            *(uint4*)(dstp + i * 8) = *(const uint4*)(srcp + i * 8);
    }
}

// ---------------- k2: scan chunk summaries -> per-chunk carry-in ------------------
__global__ __launch_bounds__(256) void k2_carry(
    const float* __restrict__ sumA, const float* __restrict__ sumB,
    float* __restrict__ carry)
{
    const int idx = blockIdx.x * 256 + threadIdx.x;  // 0..8191
    const int b = idx >> 9, h = idx & 511;
    const size_t base = (((size_t)b * 64) << 9) + h;
    float H = EPSF;
#pragma unroll
    for (int c = 0; c < 64; c += 8) {
        float av[8], bv[8];
#pragma unroll
        for (int u = 0; u < 8; ++u) {           // independent loads issue together
            const size_t o = base + ((size_t)(c + u) << 9);
            av[u] = sumA[o]; bv[u] = sumB[o];
        }
#pragma unroll
        for (int u = 0; u < 8; ++u) {
            carry[base + ((size_t)(c + u) << 9)] = H;
            H = fmaf(av[u], H, bv[u]);
        }
    }
}

// ---------------- k4: layer-1 MFMA GEMM (K=512) + transform + chunk summaries -----
// r14 structure: counted vmcnt(6) + raw barriers + (256,2) clamp, fully unrolled
// loop, hoisted addresses. Only gate_transform changed (division-free).
// Block 256 thr (4 waves, 2m x 2n), tile 128m x 128n, K_STEP 32, dbuf, grid (4,512).
__global__ __launch_bounds__(256, 2) void k4_l1(
    const __half* __restrict__ h0,
    const __half* __restrict__ Wtz, const __half* __restrict__ Wth,  // [512][512] fp16
    const float* __restrict__ bz, const float* __restrict__ bh,
    float* __restrict__ sumA, float* __restrict__ sumB)
{
    __shared__ char smem4[2][24576];     // per buf: A 8KB (128x32) + B 16KB (256x32)
    const int tid = threadIdx.x;
    const int wave = tid >> 6, lane = tid & 63;
    const int q = lane >> 4, l16 = lane & 15;
    const int wm = wave >> 1, wn = wave & 1;

    const int Lb = blockIdx.x + 4 * blockIdx.y;
    const int lin = (Lb & 7) * 256 + (Lb >> 3);
    const int bx = lin & 3, by = lin >> 2;
    const int m0 = by * 128, n0 = bx * 128;

    const int r4 = lane >> 2, ch = lane & 3;

    // hoisted staging sources (per-lane) + LDS dest byte offsets (wave-uniform)
    const __half* aSrc[2]; int aDst[2];
#pragma unroll
    for (int i = 0; i < 2; ++i) {
        const int reg = wave * 2 + i;
        const int row = reg * 16 + r4;
        const int pc = ch ^ ((row >> 1) & 3);
        aSrc[i] = h0 + (size_t)(m0 + row) * 512 + pc * 8;
        aDst[i] = reg * 1024;                         // within A region
    }
    const __half* bSrc[4]; int bDst[4];
#pragma unroll
    for (int i = 0; i < 4; ++i) {
        const int reg = wave * 4 + i;
        const int row = reg * 16 + r4;
        const int pc = ch ^ ((row >> 1) & 3);
        bSrc[i] = ((row < 128) ? (Wtz + (size_t)(n0 + row) * 512)
                               : (Wth + (size_t)(n0 + row - 128) * 512)) + pc * 8;
        bDst[i] = 8192 + reg * 1024;                  // B region starts at 8KB
    }
    // hoisted ds_read byte offsets (within one buffer)
    int aOff[4], bOff[4];
#pragma unroll
    for (int mi = 0; mi < 4; ++mi) {
        const int row = wm * 64 + mi * 16 + l16;
        aOff[mi] = row * 64 + ((q ^ ((row >> 1) & 3)) << 4);
    }
#pragma unroll
    for (int ni = 0; ni < 4; ++ni) {
        const int rn = wn * 64 + ni * 16 + l16;
        bOff[ni] = 8192 + rn * 64 + ((q ^ ((rn >> 1) & 3)) << 4);
    }

    f32x4 accz[4][4], acch[4][4];
#pragma unroll
    for (int mi = 0; mi < 4; ++mi)
#pragma unroll
        for (int ni = 0; ni < 4; ++ni) {
            accz[mi][ni] = (f32x4){0.f, 0.f, 0.f, 0.f};
            acch[mi][ni] = (f32x4){0.f, 0.f, 0.f, 0.f};
        }

    auto stage = [&](int c, int t) {     // 6 gload16; t compile-time under unroll
#pragma unroll
        for (int i = 0; i < 2; ++i)
            gload16(aSrc[i] + t * 32, smem4[c] + aDst[i]);
#pragma unroll
        for (int i = 0; i < 4; ++i)
            gload16(bSrc[i] + t * 32, smem4[c] + bDst[i]);
    };
    auto compute = [&](int c) {
        half8 af[4];
#pragma unroll
        for (int mi = 0; mi < 4; ++mi)
            af[mi] = *(const half8*)(smem4[c] + aOff[mi]);
        __builtin_amdgcn_s_setprio(1);
#pragma unroll
        for (int ni = 0; ni < 4; ++ni) {
            half8 bzf = *(const half8*)(smem4[c] + bOff[ni]);
            half8 bhf = *(const half8*)(smem4[c] + 8192 + bOff[ni]);
#pragma unroll
            for (int mi = 0; mi < 4; ++mi) {
                accz[mi][ni] = __builtin_amdgcn_mfma_f32_16x16x32_f16(af[mi], bzf, accz[mi][ni], 0, 0, 0);
                acch[mi][ni] = __builtin_amdgcn_mfma_f32_16x16x32_f16(af[mi], bhf, acch[mi][ni], 0, 0, 0);
            }
        }
        __builtin_amdgcn_s_setprio(0);
    };

    stage(0, 0);
#pragma unroll
    for (int t = 0; t < 15; ++t) {             // fully unrolled steady state
        const int c = t & 1;
        stage(c ^ 1, t + 1);                   // issue next tile (6 loads in flight)
        asm volatile("s_waitcnt vmcnt(6)" ::: "memory");   // tile t landed
        __builtin_amdgcn_s_barrier();          // tile t visible to all waves
        compute(c);
        __builtin_amdgcn_s_barrier();          // reads of buf c done (no drain)
    }
    asm volatile("s_waitcnt vmcnt(0)" ::: "memory");       // drain tile 15
    __builtin_amdgcn_s_barrier();
    compute(1);

    // epilogue: transform + chunk summary (wave wm owns chunk)
    const int bidx = by >> 5;
    const int chunkg = ((by & 31) << 1) + wm;
    const size_t srow = ((size_t)(bidx * 64 + chunkg)) << 9;
#pragma unroll
    for (int ni = 0; ni < 4; ++ni) {
        const int col = n0 + wn * 64 + ni * 16 + l16;
        const float bzv = bz[col], bhv = bh[col];
        float fullA = 1.f, fullB = 0.f;
#pragma unroll
        for (int mi = 0; mi < 4; ++mi) {
            float pA = 1.f, pB = 0.f;
#pragma unroll
            for (int j = 0; j < 4; ++j) {
                float a, b;
                gate_transform(accz[mi][ni][j] + bzv, acch[mi][ni][j] + bhv, a, b);
                pB = fmaf(a, pB, b); pA *= a;
            }
            float fA, fB, prA, prB;
            qscan(q, pA, pB, fA, fB, prA, prB);
            fullB = fmaf(fA, fullB, fB); fullA *= fA;
        }
        if (q == 0) { sumA[srow + col] = fullA; sumB[srow + col] = fullB; }
    }
}

// ---------------- k5: final chunk scan + GEMV with Wf ----------------------------
__global__ __launch_bounds__(512) void k5_final(
    const float* __restrict__ sumA, const float* __restrict__ sumB,
    const float* __restrict__ Wf, const float* __restrict__ bf,
    float* __restrict__ out)
{
    const int b = blockIdx.x, h = threadIdx.x;
    const size_t base = (((size_t)b * 64) << 9) + h;
    float H = EPSF;
#pragma unroll
    for (int c = 0; c < 64; c += 8) {
        float av[8], bv[8];
#pragma unroll
        for (int u = 0; u < 8; ++u) {
            const size_t o = base + ((size_t)(c + u) << 9);
            av[u] = sumA[o]; bv[u] = sumB[o];
        }
#pragma unroll
        for (int u = 0; u < 8; ++u) H = fmaf(av[u], H, bv[u]);
    }
    float v = H * Wf[h];
#pragma unroll
    for (int off = 32; off; off >>= 1) v += __shfl_down(v, off, 64);
    __shared__ float wsum[8];
    if ((h & 63) == 0) wsum[h >> 6] = v;
    __syncthreads();
    if (h == 0) {
        float s = 0.f;
#pragma unroll
        for (int i = 0; i < 8; ++i) s += wsum[i];
        out[b] = s + bf[0];
    }
}

extern "C" void kernel_launch(void* const* d_in, const int* in_sizes, int n_in,
                              void* d_out, int out_size, void* d_ws, size_t ws_size,
                              hipStream_t stream)
{
    const float* x   = (const float*)d_in[0];
    const float* Wz0 = (const float*)d_in[1];
    const float* bz0 = (const float*)d_in[2];
    const float* Wh0 = (const float*)d_in[3];
    const float* bh0 = (const float*)d_in[4];
    const float* Wz1 = (const float*)d_in[5];
    const float* bz1 = (const float*)d_in[6];
    const float* Wh1 = (const float*)d_in[7];
    const float* bh1 = (const float*)d_in[8];
    const float* Wf  = (const float*)d_in[9];
    const float* bf  = (const float*)d_in[10];
    float* out = (float*)d_out;

    // workspace layout (~80 MiB)
    char* ws = (char*)d_ws;
    __half* x16  = (__half*)ws;                          // 8 MiB
    __half* h0b  = (__half*)(ws + ((size_t)8 << 20));    // 64 MiB
    __half* Wtz1 = (__half*)(ws + ((size_t)72 << 20));   // 512 KiB
    __half* Wth1 = Wtz1 + 262144;                        // 512 KiB
    __half* Wtz0 = Wth1 + 262144;                        // 64 KiB
    __half* Wth0 = Wtz0 + 32768;                         // 64 KiB
    float* sumA  = (float*)(ws + ((size_t)74 << 20));    // 2 MiB
    float* sumB  = sumA + 524288;                        // 2 MiB
    float* carry = sumB + 524288;                        // 2 MiB

    kprep<<<2192, 256, 0, stream>>>(x, x16, Wz1, Wh1, Wtz1, Wth1,
                                    Wz0, Wh0, Wtz0, Wth0);
    k1_l0<0><<<dim3(8, 512), 256, 0, stream>>>(x16, Wtz0, Wth0, bz0, bh0,
                                               sumA, sumB, nullptr, nullptr);
    k2_carry<<<32, 256, 0, stream>>>(sumA, sumB, carry);
    k1_l0<1><<<dim3(8, 512), 256, 0, stream>>>(x16, Wtz0, Wth0, bz0, bh0,
                                               nullptr, nullptr, carry, h0b);
    k4_l1<<<dim3(4, 512), 256, 0, stream>>>(h0b, Wtz1, Wth1, bz1, bh1, sumA, sumB);
    k5_final<<<16, 512, 0, stream>>>(sumA, sumB, Wf, bf, out);
}

// Round 16
// 170.773 us; speedup vs baseline: 1.7563x; 1.1911x over previous
//
#include <hip/hip_runtime.h>
#include <hip/hip_fp16.h>

#define EPSF 1e-8f

typedef _Float16 half8 __attribute__((ext_vector_type(8)));
typedef float f32x4 __attribute__((ext_vector_type(4)));

// B=16, L=4096, I=64, H=512, O=1. M = B*L = 65536. CHUNK=64, NC=64.

__device__ __forceinline__ float fast_rcp(float x) {
    return __builtin_amdgcn_rcpf(x);   // v_rcp_f32, ~1 ulp
}
// transform pre-activations -> (a, b) of recurrence h = a*h + b
// division-free: sigma(x) = rcp(1+exp(-x)); 1-sigma(k) = ek*z exactly.
__device__ __forceinline__ void gate_transform(float pz, float ph, float& a, float& b) {
    float ez = __expf(-pz);
    float k  = fast_rcp(1.0f + ez);          // k = sigmoid(pz)
    float ek = __expf(-k);
    float z  = fast_rcp(1.0f + ek);          // z = sigmoid(k)
    a = ek * z;                              // a = 1 - z (exact algebra)
    float es = __expf(-ph);
    float s  = fast_rcp(1.0f + es);          // sigmoid(ph)
    float e2 = __expf(-2.0f * s);
    float hw = (1.0f - e2) * fast_rcp(1.0f + e2) + EPSF;  // tanh(s)+eps
    b = z * hw;
}

// async global->LDS, 16B per lane; LDS dest = wave-uniform base + lane*16
__device__ __forceinline__ void gload16(const void* g, void* l) {
    __builtin_amdgcn_global_load_lds(
        (const __attribute__((address_space(1))) unsigned int*)g,
        (__attribute__((address_space(3))) unsigned int*)l, 16, 0, 0);
}

// Ordered affine compose across the 4 q-subgroups of a 64-lane wave.
__device__ __forceinline__ void qscan(int q, float pA, float pB,
                                      float& fA, float& fB, float& prA, float& prB)
{
    float oA = __shfl_xor(pA, 16, 64), oB = __shfl_xor(pB, 16, 64);
    float eA = (q & 1) ? oA : pA, eB = (q & 1) ? oB : pB;   // earlier of pair
    float lA = (q & 1) ? pA : oA, lB = (q & 1) ? pB : oB;   // later of pair
    float p2A = eA * lA;
    float p2B = fmaf(lA, eB, lB);
    float o2A = __shfl_xor(p2A, 32, 64), o2B = __shfl_xor(p2B, 32, 64);
    float loA = (q & 2) ? o2A : p2A, loB = (q & 2) ? o2B : p2B;
    float hiA = (q & 2) ? p2A : o2A, hiB = (q & 2) ? p2B : o2B;
    fA = loA * hiA;
    fB = fmaf(hiA, loB, hiB);
    prA = (q & 2) ? o2A : 1.0f;
    prB = (q & 2) ? o2B : 0.0f;
    if (q & 1) { prB = fmaf(oA, prB, oB); prA *= oA; }
}

// ---------------- kprep: x f32->fp16 (blocks 0..2047) + 4 weight transposes ------
__global__ __launch_bounds__(256) void kprep(
    const float* __restrict__ x, __half* __restrict__ x16,
    const float* __restrict__ Wz1, const float* __restrict__ Wh1,
    __half* __restrict__ Wtz1, __half* __restrict__ Wth1,
    const float* __restrict__ Wz0, const float* __restrict__ Wh0,
    __half* __restrict__ Wtz0, __half* __restrict__ Wth0)
{
    __shared__ float t[64][65];
    const int tid = threadIdx.x;
    int b = blockIdx.x;
    if (b < 2048) {
        const size_t i = ((size_t)(b * 256 + tid)) * 8;
        float4 v0 = *(const float4*)&x[i];
        float4 v1 = *(const float4*)&x[i + 4];
        __half2* o = (__half2*)(x16 + i);
        o[0] = __floats2half2_rn(v0.x, v0.y);
        o[1] = __floats2half2_rn(v0.z, v0.w);
        o[2] = __floats2half2_rn(v1.x, v1.y);
        o[3] = __floats2half2_rn(v1.z, v1.w);
        return;
    }
    b -= 2048;
    const float* W; __half* Wt; int ldt, n0, k0;
    if (b < 64)       { W = Wz1; Wt = Wtz1; ldt = 512; n0 = (b & 7) * 64; k0 = (b >> 3) * 64; }
    else if (b < 128) { b -= 64;  W = Wh1; Wt = Wth1; ldt = 512; n0 = (b & 7) * 64; k0 = (b >> 3) * 64; }
    else if (b < 136) { b -= 128; W = Wz0; Wt = Wtz0; ldt = 64;  n0 = b * 64; k0 = 0; }
    else              { b -= 136; W = Wh0; Wt = Wth0; ldt = 64;  n0 = b * 64; k0 = 0; }
    const int r = tid >> 4, c4 = (tid & 15) * 4;
#pragma unroll
    for (int rr = 0; rr < 64; rr += 16)
        *(float4*)&t[rr + r][c4] = *(const float4*)&W[(size_t)(k0 + rr + r) * 512 + n0 + c4];
    __syncthreads();
#pragma unroll
    for (int rr = 0; rr < 64; rr += 16) {
        const int row = rr + r;
        __half2 h01 = __floats2half2_rn(t[c4 + 0][row], t[c4 + 1][row]);
        __half2 h23 = __floats2half2_rn(t[c4 + 2][row], t[c4 + 3][row]);
        *(__half2*)&Wt[(size_t)(n0 + row) * ldt + k0 + c4] = h01;
        *(__half2*)&Wt[(size_t)(n0 + row) * ldt + k0 + c4 + 2] = h23;
    }
}

// ---------------- k1s: layer-0 MFMA GEMM (K=64), SINGLE PASS ----------------------
// Computes GEMM+transform once. Writes: h0 with H=0 chunk scan (via LDS transpose),
// prefix products A_t for rows t<16 of each chunk (fp16, for k3c correction),
// and chunk summaries sumA/sumB. BM=128 x BN=64, 4 waves, grid (8,512).
__global__ __launch_bounds__(256) void k1s(
    const __half* __restrict__ x16,
    const __half* __restrict__ Wtz, const __half* __restrict__ Wth,  // [512][64] fp16
    const float* __restrict__ bz, const float* __restrict__ bh,
    float* __restrict__ sumA, float* __restrict__ sumB,
    __half* __restrict__ Afix, __half* __restrict__ h0)
{
    __shared__ char smem1[32768];
    __half* As = (__half*)smem1;       // [128 rows][64 k] swizzled (16 KB)
    __half* Bs = As + 128 * 64;        // [128 rows][64 k]: rows<64 z, >=64 h (16 KB)
    const int tid = threadIdx.x;
    const int wave = tid >> 6, lane = tid & 63;
    const int q = lane >> 4, l16 = lane & 15;
    const int wm = wave >> 1, wn = wave & 1;

    const int Lb = blockIdx.x + 8 * blockIdx.y;          // 0..4095
    const int lin = (Lb & 7) * 512 + (Lb >> 3);          // bijective XCD swizzle
    const int bx = lin & 7, by = lin >> 3;
    const int m0 = by * 128, n0 = bx * 64;

    {   // stage A (16 regions x 1KB) + B (16 regions); 128B rows, 8 chunks, swz ^(row&7)
        const int r8 = lane >> 3, ch = lane & 7;
#pragma unroll
        for (int i = 0; i < 4; ++i) {
            const int reg = wave * 4 + i;
            const int row = reg * 8 + r8;
            gload16(x16 + (size_t)(m0 + row) * 64 + ((ch ^ (row & 7)) << 3),
                    (char*)As + reg * 1024);
        }
#pragma unroll
        for (int i = 0; i < 4; ++i) {
            const int reg = wave * 4 + i;
            const int row = reg * 8 + r8;
            const __half* src = (row < 64) ? (Wtz + (size_t)(n0 + row) * 64)
                                           : (Wth + (size_t)(n0 + row - 64) * 64);
            gload16(src + ((ch ^ (row & 7)) << 3), (char*)Bs + reg * 1024);
        }
    }
    __syncthreads();

    f32x4 accz[4][2], acch[4][2];
#pragma unroll
    for (int mi = 0; mi < 4; ++mi)
#pragma unroll
        for (int ni = 0; ni < 2; ++ni) {
            accz[mi][ni] = (f32x4){0.f, 0.f, 0.f, 0.f};
            acch[mi][ni] = (f32x4){0.f, 0.f, 0.f, 0.f};
        }

#pragma unroll
    for (int s = 0; s < 2; ++s) {
        half8 af[4];
#pragma unroll
        for (int mi = 0; mi < 4; ++mi) {
            const int row = wm * 64 + mi * 16 + l16;
            const int pc = (s * 4 + q) ^ (row & 7);
            af[mi] = *(const half8*)&As[row * 64 + pc * 8];
        }
#pragma unroll
        for (int ni = 0; ni < 2; ++ni) {
            const int rn = wn * 32 + ni * 16 + l16;           // 0..63
            const int pc = (s * 4 + q) ^ (rn & 7);
            half8 bzf = *(const half8*)&Bs[rn * 64 + pc * 8];
            half8 bhf = *(const half8*)&Bs[(64 + rn) * 64 + pc * 8];
#pragma unroll
            for (int mi = 0; mi < 4; ++mi) {
                accz[mi][ni] = __builtin_amdgcn_mfma_f32_16x16x32_f16(af[mi], bzf, accz[mi][ni], 0, 0, 0);
                acch[mi][ni] = __builtin_amdgcn_mfma_f32_16x16x32_f16(af[mi], bhf, acch[mi][ni], 0, 0, 0);
            }
        }
    }

    // epilogue. C layout: row(m) = q*4 + j (+mi*16), col(n) = l16 (+ni*16)
    const int bidx = by >> 5;                    // 32 m-tiles per batch
    const int chunkg = ((by & 31) << 1) + wm;    // chunk within batch
    const int chunkId = bidx * 64 + chunkg;      // 0..1023
    const size_t srow = ((size_t)chunkId) << 9;

    __syncthreads();                   // done reading As/Bs -> overlay h0s
    __half* h0s = (__half*)smem1;      // [128][68] fp16, 17408 B

#pragma unroll
    for (int ni = 0; ni < 2; ++ni) {
        const int colloc = wn * 32 + ni * 16 + l16;           // 0..63
        const int col = n0 + colloc;
        const float bzv = bz[col], bhv = bh[col];
        float runA = 1.f, runB = 0.f;   // chunk-prefix compose (H = 0 scan)
#pragma unroll
        for (int mi = 0; mi < 4; ++mi) {
            float av[4], bv[4];
            float pA = 1.f, pB = 0.f;
#pragma unroll
            for (int j = 0; j < 4; ++j) {
                gate_transform(accz[mi][ni][j] + bzv, acch[mi][ni][j] + bhv, av[j], bv[j]);
                pB = fmaf(av[j], pB, bv[j]); pA *= av[j];
            }
            float fA, fB, prA, prB;
            qscan(q, pA, pB, fA, fB, prA, prB);
            float Hl = fmaf(prA, runB, prB);     // h before this lane's 4 rows (H=0)
            const int rloc = wm * 64 + mi * 16 + q * 4;
            if (mi == 0) {                       // rows t<16: also store prefix A_t
                float Ar = prA;
                const size_t abase = ((size_t)chunkId * 16 + q * 4) * 512 + col;
#pragma unroll
                for (int j = 0; j < 4; ++j) {
                    Hl = fmaf(av[j], Hl, bv[j]);
                    h0s[(rloc + j) * 68 + colloc] = (__half)Hl;
                    Ar *= av[j];
                    Afix[abase + (size_t)j * 512] = (__half)Ar;
                }
            } else {
#pragma unroll
                for (int j = 0; j < 4; ++j) {
                    Hl = fmaf(av[j], Hl, bv[j]);
                    h0s[(rloc + j) * 68 + colloc] = (__half)Hl;
                }
            }
            runB = fmaf(fA, runB, fB); runA *= fA;
        }
        if (q == 0) { sumA[srow + col] = runA; sumB[srow + col] = runB; }
    }
    __syncthreads();
    {   // coalesced h0 writeout
        const int row = tid >> 1, cpart = tid & 1;
        const __half* srcp = h0s + row * 68 + cpart * 32;
        __half* dstp = h0 + (size_t)(m0 + row) * 512 + n0 + cpart * 32;
#pragma unroll
        for (int i = 0; i < 4; ++i)
            *(uint4*)(dstp + i * 8) = *(const uint4*)(srcp + i * 8);
    }
}

// ---------------- k2: scan chunk summaries -> per-chunk carry-in ------------------
__global__ __launch_bounds__(256) void k2_carry(
    const float* __restrict__ sumA, const float* __restrict__ sumB,
    float* __restrict__ carry)
{
    const int idx = blockIdx.x * 256 + threadIdx.x;  // 0..8191
    const int b = idx >> 9, h = idx & 511;
    const size_t base = (((size_t)b * 64) << 9) + h;
    float H = EPSF;
#pragma unroll
    for (int c = 0; c < 64; c += 8) {
        float av[8], bv[8];
#pragma unroll
        for (int u = 0; u < 8; ++u) {           // independent loads issue together
            const size_t o = base + ((size_t)(c + u) << 9);
            av[u] = sumA[o]; bv[u] = sumB[o];
        }
#pragma unroll
        for (int u = 0; u < 8; ++u) {
            carry[base + ((size_t)(c + u) << 9)] = H;
            H = fmaf(av[u], H, bv[u]);
        }
    }
}

// ---------------- k3c: carry correction, rows t<16 of each chunk ------------------
// h0[row t] += A_t * carry   (A_t <= 0.5^(t+1); t>=16 contribution < 6e-6, dropped)
__global__ __launch_bounds__(256) void k3c(
    const __half* __restrict__ Afix, const float* __restrict__ carry,
    __half* __restrict__ h0)
{
    const int cb = blockIdx.x;                 // chunkId = b*64 + c, 0..1023
    const int col = threadIdx.x * 2;
    const float2 H = *(const float2*)&carry[((size_t)cb << 9) + col];
    __half2* h2 = (__half2*)(h0 + (size_t)cb * 64 * 512 + col);
    const __half2* a2 = (const __half2*)(Afix + (size_t)cb * 16 * 512 + col);
#pragma unroll
    for (int t = 0; t < 16; ++t) {
        float2 a = __half22float2(a2[t * 256]);
        float2 v = __half22float2(h2[t * 256]);
        v.x = fmaf(a.x, H.x, v.x);
        v.y = fmaf(a.y, H.y, v.y);
        h2[t * 256] = __float22half2_rn(v);
    }
}

// ---------------- k4: layer-1 MFMA GEMM (K=512) + transform + chunk summaries -----
// r15 structure unchanged: counted vmcnt(6) + raw barriers + (256,2) clamp,
// fully unrolled loop, hoisted addresses, division-free gate_transform.
__global__ __launch_bounds__(256, 2) void k4_l1(
    const __half* __restrict__ h0,
    const __half* __restrict__ Wtz, const __half* __restrict__ Wth,  // [512][512] fp16
    const float* __restrict__ bz, const float* __restrict__ bh,
    float* __restrict__ sumA, float* __restrict__ sumB)
{
    __shared__ char smem4[2][24576];     // per buf: A 8KB (128x32) + B 16KB (256x32)
    const int tid = threadIdx.x;
    const int wave = tid >> 6, lane = tid & 63;
    const int q = lane >> 4, l16 = lane & 15;
    const int wm = wave >> 1, wn = wave & 1;

    const int Lb = blockIdx.x + 4 * blockIdx.y;
    const int lin = (Lb & 7) * 256 + (Lb >> 3);
    const int bx = lin & 3, by = lin >> 2;
    const int m0 = by * 128, n0 = bx * 128;

    const int r4 = lane >> 2, ch = lane & 3;

    // hoisted staging sources (per-lane) + LDS dest byte offsets (wave-uniform)
    const __half* aSrc[2]; int aDst[2];
#pragma unroll
    for (int i = 0; i < 2; ++i) {
        const int reg = wave * 2 + i;
        const int row = reg * 16 + r4;
        const int pc = ch ^ ((row >> 1) & 3);
        aSrc[i] = h0 + (size_t)(m0 + row) * 512 + pc * 8;
        aDst[i] = reg * 1024;                         // within A region
    }
    const __half* bSrc[4]; int bDst[4];
#pragma unroll
    for (int i = 0; i < 4; ++i) {
        const int reg = wave * 4 + i;
        const int row = reg * 16 + r4;
        const int pc = ch ^ ((row >> 1) & 3);
        bSrc[i] = ((row < 128) ? (Wtz + (size_t)(n0 + row) * 512)
                               : (Wth + (size_t)(n0 + row - 128) * 512)) + pc * 8;
        bDst[i] = 8192 + reg * 1024;                  // B region starts at 8KB
    }
    // hoisted ds_read byte offsets (within one buffer)
    int aOff[4], bOff[4];
#pragma unroll
    for (int mi = 0; mi < 4; ++mi) {
        const int row = wm * 64 + mi * 16 + l16;
        aOff[mi] = row * 64 + ((q ^ ((row >> 1) & 3)) << 4);
    }
#pragma unroll
    for (int ni = 0; ni < 4; ++ni) {
        const int rn = wn * 64 + ni * 16 + l16;
        bOff[ni] = 8192 + rn * 64 + ((q ^ ((rn >> 1) & 3)) << 4);
    }

    f32x4 accz[4][4], acch[4][4];
#pragma unroll
    for (int mi = 0; mi < 4; ++mi)
#pragma unroll
        for (int ni = 0; ni < 4; ++ni) {
            accz[mi][ni] = (f32x4){0.f, 0.f, 0.f, 0.f};
            acch[mi][ni] = (f32x4){0.f, 0.f, 0.f, 0.f};
        }

    auto stage = [&](int c, int t) {     // 6 gload16; t compile-time under unroll
#pragma unroll
        for (int i = 0; i < 2; ++i)
            gload16(aSrc[i] + t * 32, smem4[c] + aDst[i]);
#pragma unroll
        for (int i = 0; i < 4; ++i)
            gload16(bSrc[i] + t * 32, smem4[c] + bDst[i]);
    };
    auto compute = [&](int c) {
        half8 af[4];
#pragma unroll
        for (int mi = 0; mi < 4; ++mi)
            af[mi] = *(const half8*)(smem4[c] + aOff[mi]);
        __builtin_amdgcn_s_setprio(1);
#pragma unroll
        for (int ni = 0; ni < 4; ++ni) {
            half8 bzf = *(const half8*)(smem4[c] + bOff[ni]);
            half8 bhf = *(const half8*)(smem4[c] + 8192 + bOff[ni]);
#pragma unroll
            for (int mi = 0; mi < 4; ++mi) {
                accz[mi][ni] = __builtin_amdgcn_mfma_f32_16x16x32_f16(af[mi], bzf, accz[mi][ni], 0, 0, 0);
                acch[mi][ni] = __builtin_amdgcn_mfma_f32_16x16x32_f16(af[mi], bhf, acch[mi][ni], 0, 0, 0);
            }
        }
        __builtin_amdgcn_s_setprio(0);
    };

    stage(0, 0);
#pragma unroll
    for (int t = 0; t < 15; ++t) {             // fully unrolled steady state
        const int c = t & 1;
        stage(c ^ 1, t + 1);                   // issue next tile (6 loads in flight)
        asm volatile("s_waitcnt vmcnt(6)" ::: "memory");   // tile t landed
        __builtin_amdgcn_s_barrier();          // tile t visible to all waves
        compute(c);
        __builtin_amdgcn_s_barrier();          // reads of buf c done (no drain)
    }
    asm volatile("s_waitcnt vmcnt(0)" ::: "memory");       // drain tile 15
    __builtin_amdgcn_s_barrier();
    compute(1);

    // epilogue: transform + chunk summary (wave wm owns chunk)
    const int bidx = by >> 5;
    const int chunkg = ((by & 31) << 1) + wm;
    const size_t srow = ((size_t)(bidx * 64 + chunkg)) << 9;
#pragma unroll
    for (int ni = 0; ni < 4; ++ni) {
        const int col = n0 + wn * 64 + ni * 16 + l16;
        const float bzv = bz[col], bhv = bh[col];
        float fullA = 1.f, fullB = 0.f;
#pragma unroll
        for (int mi = 0; mi < 4; ++mi) {
            float pA = 1.f, pB = 0.f;
#pragma unroll
            for (int j = 0; j < 4; ++j) {
                float a, b;
                gate_transform(accz[mi][ni][j] + bzv, acch[mi][ni][j] + bhv, a, b);
                pB = fmaf(a, pB, b); pA *= a;
            }
            float fA, fB, prA, prB;
            qscan(q, pA, pB, fA, fB, prA, prB);
            fullB = fmaf(fA, fullB, fB); fullA *= fA;
        }
        if (q == 0) { sumA[srow + col] = fullA; sumB[srow + col] = fullB; }
    }
}

// ---------------- k5: final chunk scan + GEMV with Wf ----------------------------
__global__ __launch_bounds__(512) void k5_final(
    const float* __restrict__ sumA, const float* __restrict__ sumB,
    const float* __restrict__ Wf, const float* __restrict__ bf,
    float* __restrict__ out)
{
    const int b = blockIdx.x, h = threadIdx.x;
    const size_t base = (((size_t)b * 64) << 9) + h;
    float H = EPSF;
#pragma unroll
    for (int c = 0; c < 64; c += 8) {
        float av[8], bv[8];
#pragma unroll
        for (int u = 0; u < 8; ++u) {
            const size_t o = base + ((size_t)(c + u) << 9);
            av[u] = sumA[o]; bv[u] = sumB[o];
        }
#pragma unroll
        for (int u = 0; u < 8; ++u) H = fmaf(av[u], H, bv[u]);
    }
    float v = H * Wf[h];
#pragma unroll
    for (int off = 32; off; off >>= 1) v += __shfl_down(v, off, 64);
    __shared__ float wsum[8];
    if ((h & 63) == 0) wsum[h >> 6] = v;
    __syncthreads();
    if (h == 0) {
        float s = 0.f;
#pragma unroll
        for (int i = 0; i < 8; ++i) s += wsum[i];
        out[b] = s + bf[0];
    }
}

extern "C" void kernel_launch(void* const* d_in, const int* in_sizes, int n_in,
                              void* d_out, int out_size, void* d_ws, size_t ws_size,
                              hipStream_t stream)
{
    const float* x   = (const float*)d_in[0];
    const float* Wz0 = (const float*)d_in[1];
    const float* bz0 = (const float*)d_in[2];
    const float* Wh0 = (const float*)d_in[3];
    const float* bh0 = (const float*)d_in[4];
    const float* Wz1 = (const float*)d_in[5];
    const float* bz1 = (const float*)d_in[6];
    const float* Wh1 = (const float*)d_in[7];
    const float* bh1 = (const float*)d_in[8];
    const float* Wf  = (const float*)d_in[9];
    const float* bf  = (const float*)d_in[10];
    float* out = (float*)d_out;

    // workspace layout (~96 MiB)
    char* ws = (char*)d_ws;
    __half* x16  = (__half*)ws;                          // 8 MiB
    __half* h0b  = (__half*)(ws + ((size_t)8 << 20));    // 64 MiB
    __half* Wtz1 = (__half*)(ws + ((size_t)72 << 20));   // 512 KiB
    __half* Wth1 = Wtz1 + 262144;                        // 512 KiB
    __half* Wtz0 = Wth1 + 262144;                        // 64 KiB
    __half* Wth0 = Wtz0 + 32768;                         // 64 KiB
    float* sumA  = (float*)(ws + ((size_t)74 << 20));    // 2 MiB
    float* sumB  = sumA + 524288;                        // 2 MiB
    float* carry = sumB + 524288;                        // 2 MiB
    __half* Afix = (__half*)(ws + ((size_t)80 << 20));   // 16 MiB

    kprep<<<2192, 256, 0, stream>>>(x, x16, Wz1, Wh1, Wtz1, Wth1,
                                    Wz0, Wh0, Wtz0, Wth0);
    k1s<<<dim3(8, 512), 256, 0, stream>>>(x16, Wtz0, Wth0, bz0, bh0,
                                          sumA, sumB, Afix, h0b);
    k2_carry<<<32, 256, 0, stream>>>(sumA, sumB, carry);
    k3c<<<1024, 256, 0, stream>>>(Afix, carry, h0b);
    k4_l1<<<dim3(4, 512), 256, 0, stream>>>(h0b, Wtz1, Wth1, bz1, bh1, sumA, sumB);
    k5_final<<<16, 512, 0, stream>>>(sumA, sumB, Wf, bf, out);
}

// Round 17
// 34.266 us; speedup vs baseline: 8.7528x; 4.9837x over previous
//
#include <hip/hip_runtime.h>
#include <hip/hip_fp16.h>

#define EPSF 1e-8f

typedef _Float16 half8 __attribute__((ext_vector_type(8)));
typedef float f32x4 __attribute__((ext_vector_type(4)));

// B=16, L=4096, I=64, H=512, O=1.
// TRUNCATION: a_t = 1-sigmoid(sigmoid(.)) < 0.5 always -> influence halves per step.
// Output = h1[:,L-1,:] @ Wf. Layer-1 window = last 64 steps (err <= 0.5^64*0.77 ~ 4e-20).
// Layer-0 computed on last 128 steps; first 64 = warm-up (same bound). 32x less work.

__device__ __forceinline__ float fast_rcp(float x) {
    return __builtin_amdgcn_rcpf(x);
}
// transform pre-activations -> (a, b) of recurrence h = a*h + b (division-free)
__device__ __forceinline__ void gate_transform(float pz, float ph, float& a, float& b) {
    float ez = __expf(-pz);
    float k  = fast_rcp(1.0f + ez);          // sigmoid(pz)
    float ek = __expf(-k);
    float z  = fast_rcp(1.0f + ek);          // sigmoid(k)
    a = ek * z;                              // 1 - z exactly
    float es = __expf(-ph);
    float s  = fast_rcp(1.0f + es);          // sigmoid(ph)
    float e2 = __expf(-2.0f * s);
    float hw = (1.0f - e2) * fast_rcp(1.0f + e2) + EPSF;  // tanh(s)+eps
    b = z * hw;
}

// async global->LDS, 16B per lane
__device__ __forceinline__ void gload16(const void* g, void* l) {
    __builtin_amdgcn_global_load_lds(
        (const __attribute__((address_space(1))) unsigned int*)g,
        (__attribute__((address_space(3))) unsigned int*)l, 16, 0, 0);
}

// Ordered affine compose across the 4 q-subgroups of a 64-lane wave.
__device__ __forceinline__ void qscan(int q, float pA, float pB,
                                      float& fA, float& fB, float& prA, float& prB)
{
    float oA = __shfl_xor(pA, 16, 64), oB = __shfl_xor(pB, 16, 64);
    float eA = (q & 1) ? oA : pA, eB = (q & 1) ? oB : pB;
    float lA = (q & 1) ? pA : oA, lB = (q & 1) ? pB : oB;
    float p2A = eA * lA;
    float p2B = fmaf(lA, eB, lB);
    float o2A = __shfl_xor(p2A, 32, 64), o2B = __shfl_xor(p2B, 32, 64);
    float loA = (q & 2) ? o2A : p2A, loB = (q & 2) ? o2B : p2B;
    float hiA = (q & 2) ? p2A : o2A, hiB = (q & 2) ? p2B : o2B;
    fA = loA * hiA;
    fB = fmaf(hiA, loB, hiB);
    prA = (q & 2) ? o2A : 1.0f;
    prB = (q & 2) ? o2B : 0.0f;
    if (q & 1) { prB = fmaf(oA, prB, oB); prA *= oA; }
}

// ---------------- kprep: x tail f32->fp16 (blocks 0..63) + weight transposes -----
__global__ __launch_bounds__(256) void kprep(
    const float* __restrict__ x, __half* __restrict__ x16r,
    const float* __restrict__ Wz1, const float* __restrict__ Wh1,
    __half* __restrict__ Wtz1, __half* __restrict__ Wth1,
    const float* __restrict__ Wz0, const float* __restrict__ Wh0,
    __half* __restrict__ Wtz0, __half* __restrict__ Wth0)
{
    __shared__ float t[64][65];
    const int tid = threadIdx.x;
    int b = blockIdx.x;
    if (b < 64) {   // x tail: last 128 steps per batch -> [16][128][64] fp16
        const int rf = b * 2048 + tid * 8;     // reduced flat element idx
        const int bb = rf >> 13;               // batch (8192 elems per batch)
        const int off = rf & 8191;
        const float* src = x + (size_t)bb * 262144 + 253952 + off;  // (4096-128)*64
        float4 v0 = *(const float4*)src;
        float4 v1 = *(const float4*)(src + 4);
        __half2* o = (__half2*)(x16r + rf);
        o[0] = __floats2half2_rn(v0.x, v0.y);
        o[1] = __floats2half2_rn(v0.z, v0.w);
        o[2] = __floats2half2_rn(v1.x, v1.y);
        o[3] = __floats2half2_rn(v1.z, v1.w);
        return;
    }
    b -= 64;
    const float* W; __half* Wt; int ldt, n0, k0;
    if (b < 64)       { W = Wz1; Wt = Wtz1; ldt = 512; n0 = (b & 7) * 64; k0 = (b >> 3) * 64; }
    else if (b < 128) { b -= 64;  W = Wh1; Wt = Wth1; ldt = 512; n0 = (b & 7) * 64; k0 = (b >> 3) * 64; }
    else if (b < 136) { b -= 128; W = Wz0; Wt = Wtz0; ldt = 64;  n0 = b * 64; k0 = 0; }
    else              { b -= 136; W = Wh0; Wt = Wth0; ldt = 64;  n0 = b * 64; k0 = 0; }
    const int r = tid >> 4, c4 = (tid & 15) * 4;
#pragma unroll
    for (int rr = 0; rr < 64; rr += 16)
        *(float4*)&t[rr + r][c4] = *(const float4*)&W[(size_t)(k0 + rr + r) * 512 + n0 + c4];
    __syncthreads();
#pragma unroll
    for (int rr = 0; rr < 64; rr += 16) {
        const int row = rr + r;
        __half2 h01 = __floats2half2_rn(t[c4 + 0][row], t[c4 + 1][row]);
        __half2 h23 = __floats2half2_rn(t[c4 + 2][row], t[c4 + 3][row]);
        *(__half2*)&Wt[(size_t)(n0 + row) * ldt + k0 + c4] = h01;
        *(__half2*)&Wt[(size_t)(n0 + row) * ldt + k0 + c4 + 2] = h23;
    }
}

// ---------------- k1s: layer-0 on 128-step windows -------------------------------
// Block = (batch by, n-tile bx): 128 rows x 64 cols, 4 waves (wm: row-half, wn: col-half).
// wm=0 rows 0..63 = warm-up: composite B passed via LDS as carry. wm=1 rows 64..127 =
// live window: scan with carry, write h0red[by*64 + t][col]. Grid (8, 16).
__global__ __launch_bounds__(256) void k1s(
    const __half* __restrict__ x16r,
    const __half* __restrict__ Wtz, const __half* __restrict__ Wth,  // [512][64] fp16
    const float* __restrict__ bz, const float* __restrict__ bh,
    __half* __restrict__ h0red)
{
    __shared__ char smem1[32768];
    __half* As = (__half*)smem1;       // [128 rows][64 k] swizzled (16 KB)
    __half* Bs = As + 128 * 64;        // [128 rows][64 k]: rows<64 z, >=64 h (16 KB)
    float* carray = (float*)(smem1 + 16384);   // 64 floats; written after sync
    __half* h0s = (__half*)smem1;      // [64][68] fp16 overlay (8704 B)
    const int tid = threadIdx.x;
    const int wave = tid >> 6, lane = tid & 63;
    const int q = lane >> 4, l16 = lane & 15;
    const int wm = wave >> 1, wn = wave & 1;

    const int bx = blockIdx.x, by = blockIdx.y;
    const int m0 = by * 128, n0 = bx * 64;

    {   // stage A (16 regions x 1KB) + B (16 regions); swz ^(row&7)
        const int r8 = lane >> 3, ch = lane & 7;
#pragma unroll
        for (int i = 0; i < 4; ++i) {
            const int reg = wave * 4 + i;
            const int row = reg * 8 + r8;
            gload16(x16r + (size_t)(m0 + row) * 64 + ((ch ^ (row & 7)) << 3),
                    (char*)As + reg * 1024);
        }
#pragma unroll
        for (int i = 0; i < 4; ++i) {
            const int reg = wave * 4 + i;
            const int row = reg * 8 + r8;
            const __half* src = (row < 64) ? (Wtz + (size_t)(n0 + row) * 64)
                                           : (Wth + (size_t)(n0 + row - 64) * 64);
            gload16(src + ((ch ^ (row & 7)) << 3), (char*)Bs + reg * 1024);
        }
    }
    __syncthreads();

    f32x4 accz[4][2], acch[4][2];
#pragma unroll
    for (int mi = 0; mi < 4; ++mi)
#pragma unroll
        for (int ni = 0; ni < 2; ++ni) {
            accz[mi][ni] = (f32x4){0.f, 0.f, 0.f, 0.f};
            acch[mi][ni] = (f32x4){0.f, 0.f, 0.f, 0.f};
        }

#pragma unroll
    for (int s = 0; s < 2; ++s) {
        half8 af[4];
#pragma unroll
        for (int mi = 0; mi < 4; ++mi) {
            const int row = wm * 64 + mi * 16 + l16;
            const int pc = (s * 4 + q) ^ (row & 7);
            af[mi] = *(const half8*)&As[row * 64 + pc * 8];
        }
#pragma unroll
        for (int ni = 0; ni < 2; ++ni) {
            const int rn = wn * 32 + ni * 16 + l16;
            const int pc = (s * 4 + q) ^ (rn & 7);
            half8 bzf = *(const half8*)&Bs[rn * 64 + pc * 8];
            half8 bhf = *(const half8*)&Bs[(64 + rn) * 64 + pc * 8];
#pragma unroll
            for (int mi = 0; mi < 4; ++mi) {
                accz[mi][ni] = __builtin_amdgcn_mfma_f32_16x16x32_f16(af[mi], bzf, accz[mi][ni], 0, 0, 0);
                acch[mi][ni] = __builtin_amdgcn_mfma_f32_16x16x32_f16(af[mi], bhf, acch[mi][ni], 0, 0, 0);
            }
        }
    }

    // ---- warm-up composite (wm=0): per-column 64-step B with H=0 ----
    float rB[2];
    if (wm == 0) {
#pragma unroll
        for (int ni = 0; ni < 2; ++ni) {
            const int col = n0 + wn * 32 + ni * 16 + l16;
            const float bzv = bz[col], bhv = bh[col];
            float runA = 1.f, runB = 0.f;
#pragma unroll
            for (int mi = 0; mi < 4; ++mi) {
                float av[4], bv[4], pA = 1.f, pB = 0.f;
#pragma unroll
                for (int j = 0; j < 4; ++j) {
                    gate_transform(accz[mi][ni][j] + bzv, acch[mi][ni][j] + bhv, av[j], bv[j]);
                    pB = fmaf(av[j], pB, bv[j]); pA *= av[j];
                }
                float fA, fB, prA, prB;
                qscan(q, pA, pB, fA, fB, prA, prB);
                runB = fmaf(fA, runB, fB); runA *= fA;
            }
            rB[ni] = runB;
        }
    }
    __syncthreads();                   // all waves done reading As/Bs
    if (wm == 0 && q == 0) {
#pragma unroll
        for (int ni = 0; ni < 2; ++ni)
            carray[wn * 32 + ni * 16 + l16] = rB[ni];
    }
    __syncthreads();                   // carry visible
    // ---- live window (wm=1): scan with carry, stage rows into h0s ----
    if (wm == 1) {
#pragma unroll
        for (int ni = 0; ni < 2; ++ni) {
            const int colloc = wn * 32 + ni * 16 + l16;
            const int col = n0 + colloc;
            const float bzv = bz[col], bhv = bh[col];
            float H = carray[colloc];
#pragma unroll
            for (int mi = 0; mi < 4; ++mi) {
                float av[4], bv[4], pA = 1.f, pB = 0.f;
#pragma unroll
                for (int j = 0; j < 4; ++j) {
                    gate_transform(accz[mi][ni][j] + bzv, acch[mi][ni][j] + bhv, av[j], bv[j]);
                    pB = fmaf(av[j], pB, bv[j]); pA *= av[j];
                }
                float fA, fB, prA, prB;
                qscan(q, pA, pB, fA, fB, prA, prB);
                float Hl = fmaf(prA, H, prB);
                const int rloc = mi * 16 + q * 4;      // 0..63
#pragma unroll
                for (int j = 0; j < 4; ++j) {
                    Hl = fmaf(av[j], Hl, bv[j]);
                    h0s[(rloc + j) * 68 + colloc] = (__half)Hl;
                }
                H = fmaf(fA, H, fB);
            }
        }
    }
    __syncthreads();
    {   // coalesced writeout: 64 rows x 64 cols fp16
        const int row = tid >> 2, cpart = tid & 3;
        const __half* srcp = h0s + row * 68 + cpart * 16;
        __half* dstp = h0red + (size_t)(by * 64 + row) * 512 + n0 + cpart * 16;
        *(uint4*)dstp = *(const uint4*)srcp;
        *(uint4*)(dstp + 8) = *(const uint4*)(srcp + 8);
    }
}

// ---------------- k4: layer-1 MFMA GEMM on the 1024 live rows ---------------------
// Grid (4, 8): m-tile 128 rows = 2 batches (wm = batch parity), n-tile 128 cols.
// Same r16 loop: counted vmcnt(6), raw barriers, (256,2) clamp, unrolled, hoisted.
// Epilogue: per-batch 64-step composite B == h1[L-1] (H1=0) -> sumB1[batch][col].
__global__ __launch_bounds__(256, 2) void k4_l1(
    const __half* __restrict__ h0red,
    const __half* __restrict__ Wtz, const __half* __restrict__ Wth,  // [512][512] fp16
    const float* __restrict__ bz, const float* __restrict__ bh,
    float* __restrict__ sumB1)
{
    __shared__ char smem4[2][24576];     // per buf: A 8KB (128x32) + B 16KB (256x32)
    const int tid = threadIdx.x;
    const int wave = tid >> 6, lane = tid & 63;
    const int q = lane >> 4, l16 = lane & 15;
    const int wm = wave >> 1, wn = wave & 1;

    const int bx = blockIdx.x, by = blockIdx.y;
    const int m0 = by * 128, n0 = bx * 128;

    const int r4 = lane >> 2, ch = lane & 3;

    const __half* aSrc[2]; int aDst[2];
#pragma unroll
    for (int i = 0; i < 2; ++i) {
        const int reg = wave * 2 + i;
        const int row = reg * 16 + r4;
        const int pc = ch ^ ((row >> 1) & 3);
        aSrc[i] = h0red + (size_t)(m0 + row) * 512 + pc * 8;
        aDst[i] = reg * 1024;
    }
    const __half* bSrc[4]; int bDst[4];
#pragma unroll
    for (int i = 0; i < 4; ++i) {
        const int reg = wave * 4 + i;
        const int row = reg * 16 + r4;
        const int pc = ch ^ ((row >> 1) & 3);
        bSrc[i] = ((row < 128) ? (Wtz + (size_t)(n0 + row) * 512)
                               : (Wth + (size_t)(n0 + row - 128) * 512)) + pc * 8;
        bDst[i] = 8192 + reg * 1024;
    }
    int aOff[4], bOff[4];
#pragma unroll
    for (int mi = 0; mi < 4; ++mi) {
        const int row = wm * 64 + mi * 16 + l16;
        aOff[mi] = row * 64 + ((q ^ ((row >> 1) & 3)) << 4);
    }
#pragma unroll
    for (int ni = 0; ni < 4; ++ni) {
        const int rn = wn * 64 + ni * 16 + l16;
        bOff[ni] = 8192 + rn * 64 + ((q ^ ((rn >> 1) & 3)) << 4);
    }

    f32x4 accz[4][4], acch[4][4];
#pragma unroll
    for (int mi = 0; mi < 4; ++mi)
#pragma unroll
        for (int ni = 0; ni < 4; ++ni) {
            accz[mi][ni] = (f32x4){0.f, 0.f, 0.f, 0.f};
            acch[mi][ni] = (f32x4){0.f, 0.f, 0.f, 0.f};
        }

    auto stage = [&](int c, int t) {
#pragma unroll
        for (int i = 0; i < 2; ++i)
            gload16(aSrc[i] + t * 32, smem4[c] + aDst[i]);
#pragma unroll
        for (int i = 0; i < 4; ++i)
            gload16(bSrc[i] + t * 32, smem4[c] + bDst[i]);
    };
    auto compute = [&](int c) {
        half8 af[4];
#pragma unroll
        for (int mi = 0; mi < 4; ++mi)
            af[mi] = *(const half8*)(smem4[c] + aOff[mi]);
        __builtin_amdgcn_s_setprio(1);
#pragma unroll
        for (int ni = 0; ni < 4; ++ni) {
            half8 bzf = *(const half8*)(smem4[c] + bOff[ni]);
            half8 bhf = *(const half8*)(smem4[c] + 8192 + bOff[ni]);
#pragma unroll
            for (int mi = 0; mi < 4; ++mi) {
                accz[mi][ni] = __builtin_amdgcn_mfma_f32_16x16x32_f16(af[mi], bzf, accz[mi][ni], 0, 0, 0);
                acch[mi][ni] = __builtin_amdgcn_mfma_f32_16x16x32_f16(af[mi], bhf, acch[mi][ni], 0, 0, 0);
            }
        }
        __builtin_amdgcn_s_setprio(0);
    };

    stage(0, 0);
#pragma unroll
    for (int t = 0; t < 15; ++t) {
        const int c = t & 1;
        stage(c ^ 1, t + 1);
        asm volatile("s_waitcnt vmcnt(6)" ::: "memory");
        __builtin_amdgcn_s_barrier();
        compute(c);
        __builtin_amdgcn_s_barrier();
    }
    asm volatile("s_waitcnt vmcnt(0)" ::: "memory");
    __builtin_amdgcn_s_barrier();
    compute(1);

    // epilogue: 64-step composite per batch (wm) -> h1[L-1] (H=0)
    const int batch = by * 2 + wm;
#pragma unroll
    for (int ni = 0; ni < 4; ++ni) {
        const int col = n0 + wn * 64 + ni * 16 + l16;
        const float bzv = bz[col], bhv = bh[col];
        float fullA = 1.f, fullB = 0.f;
#pragma unroll
        for (int mi = 0; mi < 4; ++mi) {
            float pA = 1.f, pB = 0.f;
#pragma unroll
            for (int j = 0; j < 4; ++j) {
                float a, b;
                gate_transform(accz[mi][ni][j] + bzv, acch[mi][ni][j] + bhv, a, b);
                pB = fmaf(a, pB, b); pA *= a;
            }
            float fA, fB, prA, prB;
            qscan(q, pA, pB, fA, fB, prA, prB);
            fullB = fmaf(fA, fullB, fB); fullA *= fA;
        }
        if (q == 0) sumB1[(size_t)batch * 512 + col] = fullB;
    }
}

// ---------------- k5: out[b] = h1[L-1] @ Wf + bf ---------------------------------
__global__ __launch_bounds__(512) void k5_final(
    const float* __restrict__ sumB1,
    const float* __restrict__ Wf, const float* __restrict__ bf,
    float* __restrict__ out)
{
    const int b = blockIdx.x, h = threadIdx.x;
    float v = sumB1[(size_t)b * 512 + h] * Wf[h];
#pragma unroll
    for (int off = 32; off; off >>= 1) v += __shfl_down(v, off, 64);
    __shared__ float wsum[8];
    if ((h & 63) == 0) wsum[h >> 6] = v;
    __syncthreads();
    if (h == 0) {
        float s = 0.f;
#pragma unroll
        for (int i = 0; i < 8; ++i) s += wsum[i];
        out[b] = s + bf[0];
    }
}

extern "C" void kernel_launch(void* const* d_in, const int* in_sizes, int n_in,
                              void* d_out, int out_size, void* d_ws, size_t ws_size,
                              hipStream_t stream)
{
    const float* x   = (const float*)d_in[0];
    const float* Wz0 = (const float*)d_in[1];
    const float* bz0 = (const float*)d_in[2];
    const float* Wh0 = (const float*)d_in[3];
    const float* bh0 = (const float*)d_in[4];
    const float* Wz1 = (const float*)d_in[5];
    const float* bz1 = (const float*)d_in[6];
    const float* Wh1 = (const float*)d_in[7];
    const float* bh1 = (const float*)d_in[8];
    const float* Wf  = (const float*)d_in[9];
    const float* bf  = (const float*)d_in[10];
    float* out = (float*)d_out;

    // workspace (~3 MiB)
    char* ws = (char*)d_ws;
    __half* x16r  = (__half*)ws;                           // 256 KiB: [16][128][64]
    __half* h0red = (__half*)(ws + (512 << 10));           // 1 MiB:   [1024][512]
    __half* Wtz1  = (__half*)(ws + (1536 << 10));          // 512 KiB
    __half* Wth1  = Wtz1 + 262144;                         // 512 KiB
    __half* Wtz0  = Wth1 + 262144;                         // 64 KiB
    __half* Wth0  = Wtz0 + 32768;                          // 64 KiB
    float* sumB1  = (float*)(ws + (2688 << 10));           // 32 KiB: [16][512]

    kprep<<<208, 256, 0, stream>>>(x, x16r, Wz1, Wh1, Wtz1, Wth1,
                                   Wz0, Wh0, Wtz0, Wth0);
    k1s<<<dim3(8, 16), 256, 0, stream>>>(x16r, Wtz0, Wth0, bz0, bh0, h0red);
    k4_l1<<<dim3(4, 8), 256, 0, stream>>>(h0red, Wtz1, Wth1, bz1, bh1, sumB1);
    k5_final<<<16, 512, 0, stream>>>(sumB1, Wf, bf, out);
}

// Round 18
// 33.097 us; speedup vs baseline: 9.0621x; 1.0353x over previous
//
#include <hip/hip_runtime.h>
#include <hip/hip_fp16.h>

#define EPSF 1e-8f

typedef _Float16 half8 __attribute__((ext_vector_type(8)));
typedef float f32x4 __attribute__((ext_vector_type(4)));

// B=16, L=4096, I=64, H=512, O=1.
// TRUNCATION: a_t = 1-sigmoid(sigmoid(.)) < 0.5 always -> influence halves per step.
// Output = h1[:,L-1,:] @ Wf. Layer-1 window = last 64 steps (err <= 0.5^64*0.77 ~ 4e-20).
// Layer-0 computed on last 128 steps; first 64 = warm-up. 3 kernels total.

__device__ __forceinline__ float fast_rcp(float x) {
    return __builtin_amdgcn_rcpf(x);
}
// transform pre-activations -> (a, b) of recurrence h = a*h + b (division-free)
__device__ __forceinline__ void gate_transform(float pz, float ph, float& a, float& b) {
    float ez = __expf(-pz);
    float k  = fast_rcp(1.0f + ez);          // sigmoid(pz)
    float ek = __expf(-k);
    float z  = fast_rcp(1.0f + ek);          // sigmoid(k)
    a = ek * z;                              // 1 - z exactly
    float es = __expf(-ph);
    float s  = fast_rcp(1.0f + es);          // sigmoid(ph)
    float e2 = __expf(-2.0f * s);
    float hw = (1.0f - e2) * fast_rcp(1.0f + e2) + EPSF;  // tanh(s)+eps
    b = z * hw;
}

// async global->LDS, 16B per lane
__device__ __forceinline__ void gload16(const void* g, void* l) {
    __builtin_amdgcn_global_load_lds(
        (const __attribute__((address_space(1))) unsigned int*)g,
        (__attribute__((address_space(3))) unsigned int*)l, 16, 0, 0);
}

// Ordered affine compose across the 4 q-subgroups of a 64-lane wave.
__device__ __forceinline__ void qscan(int q, float pA, float pB,
                                      float& fA, float& fB, float& prA, float& prB)
{
    float oA = __shfl_xor(pA, 16, 64), oB = __shfl_xor(pB, 16, 64);
    float eA = (q & 1) ? oA : pA, eB = (q & 1) ? oB : pB;
    float lA = (q & 1) ? pA : oA, lB = (q & 1) ? pB : oB;
    float p2A = eA * lA;
    float p2B = fmaf(lA, eB, lB);
    float o2A = __shfl_xor(p2A, 32, 64), o2B = __shfl_xor(p2B, 32, 64);
    float loA = (q & 2) ? o2A : p2A, loB = (q & 2) ? o2B : p2B;
    float hiA = (q & 2) ? p2A : o2A, hiB = (q & 2) ? p2B : o2B;
    fA = loA * hiA;
    fB = fmaf(hiA, loB, hiB);
    prA = (q & 2) ? o2A : 1.0f;
    prB = (q & 2) ? o2B : 0.0f;
    if (q & 1) { prB = fmaf(oA, prB, oB); prA *= oA; }
}

// ---------------- kprep: weight transposes (144 blocks) + out init ----------------
__global__ __launch_bounds__(256) void kprep(
    const float* __restrict__ Wz1, const float* __restrict__ Wh1,
    __half* __restrict__ Wtz1, __half* __restrict__ Wth1,
    const float* __restrict__ Wz0, const float* __restrict__ Wh0,
    __half* __restrict__ Wtz0, __half* __restrict__ Wth0,
    const float* __restrict__ bf, float* __restrict__ out)
{
    __shared__ float t[64][65];
    const int tid = threadIdx.x;
    int b = blockIdx.x;
    if (b == 0 && tid < 16) out[tid] = bf[0];   // k4 atomically accumulates on top
    const float* W; __half* Wt; int ldt, n0, k0;
    if (b < 64)       { W = Wz1; Wt = Wtz1; ldt = 512; n0 = (b & 7) * 64; k0 = (b >> 3) * 64; }
    else if (b < 128) { b -= 64;  W = Wh1; Wt = Wth1; ldt = 512; n0 = (b & 7) * 64; k0 = (b >> 3) * 64; }
    else if (b < 136) { b -= 128; W = Wz0; Wt = Wtz0; ldt = 64;  n0 = b * 64; k0 = 0; }
    else              { b -= 136; W = Wh0; Wt = Wth0; ldt = 64;  n0 = b * 64; k0 = 0; }
    const int r = tid >> 4, c4 = (tid & 15) * 4;
#pragma unroll
    for (int rr = 0; rr < 64; rr += 16)
        *(float4*)&t[rr + r][c4] = *(const float4*)&W[(size_t)(k0 + rr + r) * 512 + n0 + c4];
    __syncthreads();
#pragma unroll
    for (int rr = 0; rr < 64; rr += 16) {
        const int row = rr + r;
        __half2 h01 = __floats2half2_rn(t[c4 + 0][row], t[c4 + 1][row]);
        __half2 h23 = __floats2half2_rn(t[c4 + 2][row], t[c4 + 3][row]);
        *(__half2*)&Wt[(size_t)(n0 + row) * ldt + k0 + c4] = h01;
        *(__half2*)&Wt[(size_t)(n0 + row) * ldt + k0 + c4 + 2] = h23;
    }
}

// ---------------- k1s: layer-0 on 128-step windows (x loaded f32 directly) --------
// Block = (n-tile bx, batch by): 128 rows x 64 cols, 4 waves (wm row-half, wn col-half).
// wm=0 rows = warm-up composite -> LDS carry; wm=1 rows = live window -> h0red.
__global__ __launch_bounds__(256) void k1s(
    const float* __restrict__ x,
    const __half* __restrict__ Wtz, const __half* __restrict__ Wth,  // [512][64] fp16
    const float* __restrict__ bz, const float* __restrict__ bh,
    __half* __restrict__ h0red)
{
    __shared__ char smem1[32768];
    __half* As = (__half*)smem1;       // [128 rows][64 k] swizzled (16 KB)
    __half* Bs = As + 128 * 64;        // [128 rows][64 k]: rows<64 z, >=64 h (16 KB)
    float* carray = (float*)(smem1 + 16384);   // 64 floats; written after sync
    __half* h0s = (__half*)smem1;      // [64][68] fp16 overlay
    const int tid = threadIdx.x;
    const int wave = tid >> 6, lane = tid & 63;
    const int q = lane >> 4, l16 = lane & 15;
    const int wm = wave >> 1, wn = wave & 1;

    const int bx = blockIdx.x, by = blockIdx.y;
    const int n0 = bx * 64;
    const float* xsrc = x + (size_t)by * 262144 + 253952;   // (4096-128)*64

    {   // stage: B via async gload16; A from f32 x tail (convert + ds_write).
        const int r8 = lane >> 3, ch = lane & 7;
#pragma unroll
        for (int i = 0; i < 4; ++i) {
            const int reg = wave * 4 + i;
            const int row = reg * 8 + r8;
            const __half* src = (row < 64) ? (Wtz + (size_t)(n0 + row) * 64)
                                           : (Wth + (size_t)(n0 + row - 64) * 64);
            gload16(src + ((ch ^ (row & 7)) << 3), (char*)Bs + reg * 1024);
        }
#pragma unroll
        for (int i = 0; i < 4; ++i) {
            const int reg = wave * 4 + i;
            const int row = reg * 8 + r8;
            const int c0 = (ch ^ (row & 7)) * 8;
            float4 v0 = *(const float4*)(xsrc + row * 64 + c0);
            float4 v1 = *(const float4*)(xsrc + row * 64 + c0 + 4);
            __half2* dst = (__half2*)((char*)As + reg * 1024 + lane * 16);
            dst[0] = __floats2half2_rn(v0.x, v0.y);
            dst[1] = __floats2half2_rn(v0.z, v0.w);
            dst[2] = __floats2half2_rn(v1.x, v1.y);
            dst[3] = __floats2half2_rn(v1.z, v1.w);
        }
    }
    __syncthreads();

    f32x4 accz[4][2], acch[4][2];
#pragma unroll
    for (int mi = 0; mi < 4; ++mi)
#pragma unroll
        for (int ni = 0; ni < 2; ++ni) {
            accz[mi][ni] = (f32x4){0.f, 0.f, 0.f, 0.f};
            acch[mi][ni] = (f32x4){0.f, 0.f, 0.f, 0.f};
        }

#pragma unroll
    for (int s = 0; s < 2; ++s) {
        half8 af[4];
#pragma unroll
        for (int mi = 0; mi < 4; ++mi) {
            const int row = wm * 64 + mi * 16 + l16;
            const int pc = (s * 4 + q) ^ (row & 7);
            af[mi] = *(const half8*)&As[row * 64 + pc * 8];
        }
#pragma unroll
        for (int ni = 0; ni < 2; ++ni) {
            const int rn = wn * 32 + ni * 16 + l16;
            const int pc = (s * 4 + q) ^ (rn & 7);
            half8 bzf = *(const half8*)&Bs[rn * 64 + pc * 8];
            half8 bhf = *(const half8*)&Bs[(64 + rn) * 64 + pc * 8];
#pragma unroll
            for (int mi = 0; mi < 4; ++mi) {
                accz[mi][ni] = __builtin_amdgcn_mfma_f32_16x16x32_f16(af[mi], bzf, accz[mi][ni], 0, 0, 0);
                acch[mi][ni] = __builtin_amdgcn_mfma_f32_16x16x32_f16(af[mi], bhf, acch[mi][ni], 0, 0, 0);
            }
        }
    }

    // ---- warm-up composite (wm=0): per-column 64-step B with H=0 ----
    float rB[2];
    if (wm == 0) {
#pragma unroll
        for (int ni = 0; ni < 2; ++ni) {
            const int col = n0 + wn * 32 + ni * 16 + l16;
            const float bzv = bz[col], bhv = bh[col];
            float runA = 1.f, runB = 0.f;
#pragma unroll
            for (int mi = 0; mi < 4; ++mi) {
                float av[4], bv[4], pA = 1.f, pB = 0.f;
#pragma unroll
                for (int j = 0; j < 4; ++j) {
                    gate_transform(accz[mi][ni][j] + bzv, acch[mi][ni][j] + bhv, av[j], bv[j]);
                    pB = fmaf(av[j], pB, bv[j]); pA *= av[j];
                }
                float fA, fB, prA, prB;
                qscan(q, pA, pB, fA, fB, prA, prB);
                runB = fmaf(fA, runB, fB); runA *= fA;
            }
            rB[ni] = runB;
        }
    }
    __syncthreads();                   // all waves done reading As/Bs
    if (wm == 0 && q == 0) {
#pragma unroll
        for (int ni = 0; ni < 2; ++ni)
            carray[wn * 32 + ni * 16 + l16] = rB[ni];
    }
    __syncthreads();                   // carry visible
    // ---- live window (wm=1): scan with carry, stage rows into h0s ----
    if (wm == 1) {
#pragma unroll
        for (int ni = 0; ni < 2; ++ni) {
            const int colloc = wn * 32 + ni * 16 + l16;
            const int col = n0 + colloc;
            const float bzv = bz[col], bhv = bh[col];
            float H = carray[colloc];
#pragma unroll
            for (int mi = 0; mi < 4; ++mi) {
                float av[4], bv[4], pA = 1.f, pB = 0.f;
#pragma unroll
                for (int j = 0; j < 4; ++j) {
                    gate_transform(accz[mi][ni][j] + bzv, acch[mi][ni][j] + bhv, av[j], bv[j]);
                    pB = fmaf(av[j], pB, bv[j]); pA *= av[j];
                }
                float fA, fB, prA, prB;
                qscan(q, pA, pB, fA, fB, prA, prB);
                float Hl = fmaf(prA, H, prB);
                const int rloc = mi * 16 + q * 4;      // 0..63
#pragma unroll
                for (int j = 0; j < 4; ++j) {
                    Hl = fmaf(av[j], Hl, bv[j]);
                    h0s[(rloc + j) * 68 + colloc] = (__half)Hl;
                }
                H = fmaf(fA, H, fB);
            }
        }
    }
    __syncthreads();
    {   // coalesced writeout: 64 rows x 64 cols fp16
        const int row = tid >> 2, cpart = tid & 3;
        const __half* srcp = h0s + row * 68 + cpart * 16;
        __half* dstp = h0red + (size_t)(by * 64 + row) * 512 + n0 + cpart * 16;
        *(uint4*)dstp = *(const uint4*)srcp;
        *(uint4*)(dstp + 8) = *(const uint4*)(srcp + 8);
    }
}

// ---------------- k4: layer-1 MFMA + fused output GEMV ----------------------------
// Grid (4, 8): m-tile 128 rows = 2 batches (wm = batch parity), n-tile 128 cols.
// r16 loop (counted vmcnt(6), raw barriers, (256,2) clamp, unrolled, hoisted).
// Epilogue: per-batch 64-step composite B == h1[L-1]; partial dot with Wf,
// wave-reduce, atomicAdd into out[batch] (init'd to bf by kprep).
__global__ __launch_bounds__(256, 2) void k4_l1(
    const __half* __restrict__ h0red,
    const __half* __restrict__ Wtz, const __half* __restrict__ Wth,  // [512][512] fp16
    const float* __restrict__ bz, const float* __restrict__ bh,
    const float* __restrict__ Wf, float* __restrict__ out)
{
    __shared__ char smem4[2][24576];     // per buf: A 8KB (128x32) + B 16KB (256x32)
    const int tid = threadIdx.x;
    const int wave = tid >> 6, lane = tid & 63;
    const int q = lane >> 4, l16 = lane & 15;
    const int wm = wave >> 1, wn = wave & 1;

    const int bx = blockIdx.x, by = blockIdx.y;
    const int m0 = by * 128, n0 = bx * 128;

    const int r4 = lane >> 2, ch = lane & 3;

    const __half* aSrc[2]; int aDst[2];
#pragma unroll
    for (int i = 0; i < 2; ++i) {
        const int reg = wave * 2 + i;
        const int row = reg * 16 + r4;
        const int pc = ch ^ ((row >> 1) & 3);
        aSrc[i] = h0red + (size_t)(m0 + row) * 512 + pc * 8;
        aDst[i] = reg * 1024;
    }
    const __half* bSrc[4]; int bDst[4];
#pragma unroll
    for (int i = 0; i < 4; ++i) {
        const int reg = wave * 4 + i;
        const int row = reg * 16 + r4;
        const int pc = ch ^ ((row >> 1) & 3);
        bSrc[i] = ((row < 128) ? (Wtz + (size_t)(n0 + row) * 512)
                               : (Wth + (size_t)(n0 + row - 128) * 512)) + pc * 8;
        bDst[i] = 8192 + reg * 1024;
    }
    int aOff[4], bOff[4];
#pragma unroll
    for (int mi = 0; mi < 4; ++mi) {
        const int row = wm * 64 + mi * 16 + l16;
        aOff[mi] = row * 64 + ((q ^ ((row >> 1) & 3)) << 4);
    }
#pragma unroll
    for (int ni = 0; ni < 4; ++ni) {
        const int rn = wn * 64 + ni * 16 + l16;
        bOff[ni] = 8192 + rn * 64 + ((q ^ ((rn >> 1) & 3)) << 4);
    }

    f32x4 accz[4][4], acch[4][4];
#pragma unroll
    for (int mi = 0; mi < 4; ++mi)
#pragma unroll
        for (int ni = 0; ni < 4; ++ni) {
            accz[mi][ni] = (f32x4){0.f, 0.f, 0.f, 0.f};
            acch[mi][ni] = (f32x4){0.f, 0.f, 0.f, 0.f};
        }

    auto stage = [&](int c, int t) {
#pragma unroll
        for (int i = 0; i < 2; ++i)
            gload16(aSrc[i] + t * 32, smem4[c] + aDst[i]);
#pragma unroll
        for (int i = 0; i < 4; ++i)
            gload16(bSrc[i] + t * 32, smem4[c] + bDst[i]);
    };
    auto compute = [&](int c) {
        half8 af[4];
#pragma unroll
        for (int mi = 0; mi < 4; ++mi)
            af[mi] = *(const half8*)(smem4[c] + aOff[mi]);
        __builtin_amdgcn_s_setprio(1);
#pragma unroll
        for (int ni = 0; ni < 4; ++ni) {
            half8 bzf = *(const half8*)(smem4[c] + bOff[ni]);
            half8 bhf = *(const half8*)(smem4[c] + 8192 + bOff[ni]);
#pragma unroll
            for (int mi = 0; mi < 4; ++mi) {
                accz[mi][ni] = __builtin_amdgcn_mfma_f32_16x16x32_f16(af[mi], bzf, accz[mi][ni], 0, 0, 0);
                acch[mi][ni] = __builtin_amdgcn_mfma_f32_16x16x32_f16(af[mi], bhf, acch[mi][ni], 0, 0, 0);
            }
        }
        __builtin_amdgcn_s_setprio(0);
    };

    stage(0, 0);
#pragma unroll
    for (int t = 0; t < 15; ++t) {
        const int c = t & 1;
        stage(c ^ 1, t + 1);
        asm volatile("s_waitcnt vmcnt(6)" ::: "memory");
        __builtin_amdgcn_s_barrier();
        compute(c);
        __builtin_amdgcn_s_barrier();
    }
    asm volatile("s_waitcnt vmcnt(0)" ::: "memory");
    __builtin_amdgcn_s_barrier();
    compute(1);

    // epilogue: 64-step composite per batch (wm) -> h1[L-1]; fused GEMV with Wf
    const int batch = by * 2 + wm;
    float part = 0.f;
#pragma unroll
    for (int ni = 0; ni < 4; ++ni) {
        const int col = n0 + wn * 64 + ni * 16 + l16;
        const float bzv = bz[col], bhv = bh[col];
        float fullA = 1.f, fullB = 0.f;
#pragma unroll
        for (int mi = 0; mi < 4; ++mi) {
            float pA = 1.f, pB = 0.f;
#pragma unroll
            for (int j = 0; j < 4; ++j) {
                float a, b;
                gate_transform(accz[mi][ni][j] + bzv, acch[mi][ni][j] + bhv, a, b);
                pB = fmaf(a, pB, b); pA *= a;
            }
            float fA, fB, prA, prB;
            qscan(q, pA, pB, fA, fB, prA, prB);
            fullB = fmaf(fA, fullB, fB); fullA *= fA;
        }
        if (q == 0) part = fmaf(fullB, Wf[col], part);
    }
#pragma unroll
    for (int off = 32; off; off >>= 1) part += __shfl_down(part, off, 64);
    if (lane == 0) atomicAdd(&out[batch], part);
}

extern "C" void kernel_launch(void* const* d_in, const int* in_sizes, int n_in,
                              void* d_out, int out_size, void* d_ws, size_t ws_size,
                              hipStream_t stream)
{
    const float* x   = (const float*)d_in[0];
    const float* Wz0 = (const float*)d_in[1];
    const float* bz0 = (const float*)d_in[2];
    const float* Wh0 = (const float*)d_in[3];
    const float* bh0 = (const float*)d_in[4];
    const float* Wz1 = (const float*)d_in[5];
    const float* bz1 = (const float*)d_in[6];
    const float* Wh1 = (const float*)d_in[7];
    const float* bh1 = (const float*)d_in[8];
    const float* Wf  = (const float*)d_in[9];
    const float* bf  = (const float*)d_in[10];
    float* out = (float*)d_out;

    // workspace (~2.2 MiB)
    char* ws = (char*)d_ws;
    __half* h0red = (__half*)ws;                           // 1 MiB: [1024][512]
    __half* Wtz1  = (__half*)(ws + (1024 << 10));          // 512 KiB
    __half* Wth1  = Wtz1 + 262144;                         // 512 KiB
    __half* Wtz0  = Wth1 + 262144;                         // 64 KiB
    __half* Wth0  = Wtz0 + 32768;                          // 64 KiB

    kprep<<<144, 256, 0, stream>>>(Wz1, Wh1, Wtz1, Wth1,
                                   Wz0, Wh0, Wtz0, Wth0, bf, out);
    k1s<<<dim3(8, 16), 256, 0, stream>>>(x, Wtz0, Wth0, bz0, bh0, h0red);
    k4_l1<<<dim3(4, 8), 256, 0, stream>>>(h0red, Wtz1, Wth1, bz1, bh1, Wf, out);
}

// Round 19
// 31.692 us; speedup vs baseline: 9.4636x; 1.0443x over previous
//
#include <hip/hip_runtime.h>
#include <hip/hip_fp16.h>

#define EPSF 1e-8f

typedef _Float16 half8 __attribute__((ext_vector_type(8)));
typedef float f32x4 __attribute__((ext_vector_type(4)));

// B=16, L=4096, I=64, H=512, O=1.
// TRUNCATION: a_t = 1-sigmoid(sigmoid(.)) < 0.5 always -> influence halves per step.
// Output = h1[:,L-1,:] @ Wf. Layer-1 window = last 64 steps (err <= 0.5^64*0.77 ~ 4e-20).
// Layer-0 computed on last 128 steps; first 64 = warm-up. TWO kernels total:
// k1s also transposes W1 (1:1 block<->tile) and stages W0 in-LDS (no kprep).

__device__ __forceinline__ float fast_rcp(float x) {
    return __builtin_amdgcn_rcpf(x);
}
// transform pre-activations -> (a, b) of recurrence h = a*h + b (division-free)
__device__ __forceinline__ void gate_transform(float pz, float ph, float& a, float& b) {
    float ez = __expf(-pz);
    float k  = fast_rcp(1.0f + ez);          // sigmoid(pz)
    float ek = __expf(-k);
    float z  = fast_rcp(1.0f + ek);          // sigmoid(k)
    a = ek * z;                              // 1 - z exactly
    float es = __expf(-ph);
    float s  = fast_rcp(1.0f + es);          // sigmoid(ph)
    float e2 = __expf(-2.0f * s);
    float hw = (1.0f - e2) * fast_rcp(1.0f + e2) + EPSF;  // tanh(s)+eps
    b = z * hw;
}

// async global->LDS, 16B per lane
__device__ __forceinline__ void gload16(const void* g, void* l) {
    __builtin_amdgcn_global_load_lds(
        (const __attribute__((address_space(1))) unsigned int*)g,
        (__attribute__((address_space(3))) unsigned int*)l, 16, 0, 0);
}

// Ordered affine compose across the 4 q-subgroups of a 64-lane wave.
__device__ __forceinline__ void qscan(int q, float pA, float pB,
                                      float& fA, float& fB, float& prA, float& prB)
{
    float oA = __shfl_xor(pA, 16, 64), oB = __shfl_xor(pB, 16, 64);
    float eA = (q & 1) ? oA : pA, eB = (q & 1) ? oB : pB;
    float lA = (q & 1) ? pA : oA, lB = (q & 1) ? pB : oB;
    float p2A = eA * lA;
    float p2B = fmaf(lA, eB, lB);
    float o2A = __shfl_xor(p2A, 32, 64), o2B = __shfl_xor(p2B, 32, 64);
    float loA = (q & 2) ? o2A : p2A, loB = (q & 2) ? o2B : p2B;
    float hiA = (q & 2) ? p2A : o2A, hiB = (q & 2) ? p2B : o2B;
    fA = loA * hiA;
    fB = fmaf(hiA, loB, hiB);
    prA = (q & 2) ? o2A : 1.0f;
    prB = (q & 2) ? o2B : 0.0f;
    if (q & 1) { prB = fmaf(oA, prB, oB); prA *= oA; }
}

// ---------------- k1s: layer-0 + W1 transpose + W0 in-LDS staging ----------------
// Grid (8,16) = 128 blocks. Block (bx,by): batch by, cols n0=bx*64, rows = last 128
// steps (wm=0 warm-up -> LDS carry, wm=1 live -> h0red). Additionally each block
// transposes ONE 64x64 tile of W1 (Lb = bx+8*by -> mat/tile) for k4.
__global__ __launch_bounds__(256) void k1s(
    const float* __restrict__ x,
    const float* __restrict__ Wz0, const float* __restrict__ Wh0,
    const float* __restrict__ Wz1, const float* __restrict__ Wh1,
    const float* __restrict__ bz, const float* __restrict__ bh,
    const float* __restrict__ bf,
    __half* __restrict__ Wtz1, __half* __restrict__ Wth1,
    __half* __restrict__ h0red, float* __restrict__ out)
{
    __shared__ char smem1[49408];
    __half* As = (__half*)smem1;               // [128 rows][64 k] swizzled (16 KB)
    __half* Bs = As + 128 * 64;                // [128 rows][64 k]: <64 z, >=64 h (16 KB)
    float (*t)[65] = (float(*)[65])(smem1 + 32768);   // 64x65 f32 staging (16.6 KB)
    float* carray = (float*)(smem1 + 16384);   // overlay on Bs; written post-MFMA
    __half* h0s = (__half*)smem1;              // overlay on As; written post-MFMA
    const int tid = threadIdx.x;
    const int wave = tid >> 6, lane = tid & 63;
    const int q = lane >> 4, l16 = lane & 15;
    const int wm = wave >> 1, wn = wave & 1;

    const int bx = blockIdx.x, by = blockIdx.y;
    const int Lb = bx + 8 * by;                // 0..127
    const int n0 = bx * 64;
    const float* xsrc = x + (size_t)by * 262144 + 253952;   // (4096-128)*64

    if (Lb == 0 && tid < 16) out[tid] = bf[0];  // k4 atomics accumulate on top

    {   // stage A: x tail f32 -> fp16 ds_write into swizzled As
        const int r8 = lane >> 3, ch = lane & 7;
#pragma unroll
        for (int i = 0; i < 4; ++i) {
            const int reg = wave * 4 + i;
            const int row = reg * 8 + r8;
            const int c0 = (ch ^ (row & 7)) * 8;
            float4 v0 = *(const float4*)(xsrc + row * 64 + c0);
            float4 v1 = *(const float4*)(xsrc + row * 64 + c0 + 4);
            __half2* dst = (__half2*)((char*)As + reg * 1024 + lane * 16);
            dst[0] = __floats2half2_rn(v0.x, v0.y);
            dst[1] = __floats2half2_rn(v0.z, v0.w);
            dst[2] = __floats2half2_rn(v1.x, v1.y);
            dst[3] = __floats2half2_rn(v1.z, v1.w);
        }
    }

    const int r = tid >> 4, c4 = (tid & 15) * 4;
    {   // W1 transpose: this block's tile (mat = Lb>>6, ti = Lb&63)
        const int mat = Lb >> 6, ti = Lb & 63;
        const int n0t = (ti & 7) * 64, k0t = (ti >> 3) * 64;
        const float* W = mat ? Wh1 : Wz1;
        __half* Wt = mat ? Wth1 : Wtz1;
#pragma unroll
        for (int rr = 0; rr < 64; rr += 16)
            *(float4*)&t[rr + r][c4] = *(const float4*)&W[(size_t)(k0t + rr + r) * 512 + n0t + c4];
        __syncthreads();
#pragma unroll
        for (int rr = 0; rr < 64; rr += 16) {
            const int row = rr + r;
            __half2 h01 = __floats2half2_rn(t[c4 + 0][row], t[c4 + 1][row]);
            __half2 h23 = __floats2half2_rn(t[c4 + 2][row], t[c4 + 3][row]);
            *(__half2*)&Wt[(size_t)(n0t + row) * 512 + k0t + c4] = h01;
            *(__half2*)&Wt[(size_t)(n0t + row) * 512 + k0t + c4 + 2] = h23;
        }
    }
    {   // W0 staging: load f32 tile -> t, transpose-convert into swizzled Bs
        const int n = tid & 63, cw = (tid >> 6) * 2;
#pragma unroll
        for (int mat = 0; mat < 2; ++mat) {
            const float* W = mat ? Wh0 : Wz0;
            __syncthreads();                   // prev t reads done
#pragma unroll
            for (int rr = 0; rr < 64; rr += 16)
                *(float4*)&t[rr + r][c4] = *(const float4*)&W[(size_t)(rr + r) * 512 + n0 + c4];
            __syncthreads();                   // t loaded
#pragma unroll
            for (int cc = 0; cc < 2; ++cc) {
                const int chunk = cw + cc;     // logical k-chunk 0..7
                half8 hv;
#pragma unroll
                for (int j = 0; j < 8; ++j) hv[j] = (_Float16)t[chunk * 8 + j][n];
                *(half8*)&Bs[(mat * 64 + n) * 64 + ((chunk ^ (n & 7)) << 3)] = hv;
            }
        }
    }
    __syncthreads();   // As + Bs ready

    f32x4 accz[4][2], acch[4][2];
#pragma unroll
    for (int mi = 0; mi < 4; ++mi)
#pragma unroll
        for (int ni = 0; ni < 2; ++ni) {
            accz[mi][ni] = (f32x4){0.f, 0.f, 0.f, 0.f};
            acch[mi][ni] = (f32x4){0.f, 0.f, 0.f, 0.f};
        }

#pragma unroll
    for (int s = 0; s < 2; ++s) {
        half8 af[4];
#pragma unroll
        for (int mi = 0; mi < 4; ++mi) {
            const int row = wm * 64 + mi * 16 + l16;
            const int pc = (s * 4 + q) ^ (row & 7);
            af[mi] = *(const half8*)&As[row * 64 + pc * 8];
        }
#pragma unroll
        for (int ni = 0; ni < 2; ++ni) {
            const int rn = wn * 32 + ni * 16 + l16;
            const int pc = (s * 4 + q) ^ (rn & 7);
            half8 bzf = *(const half8*)&Bs[rn * 64 + pc * 8];
            half8 bhf = *(const half8*)&Bs[(64 + rn) * 64 + pc * 8];
#pragma unroll
            for (int mi = 0; mi < 4; ++mi) {
                accz[mi][ni] = __builtin_amdgcn_mfma_f32_16x16x32_f16(af[mi], bzf, accz[mi][ni], 0, 0, 0);
                acch[mi][ni] = __builtin_amdgcn_mfma_f32_16x16x32_f16(af[mi], bhf, acch[mi][ni], 0, 0, 0);
            }
        }
    }

    // ---- warm-up composite (wm=0): per-column 64-step B with H=0 ----
    float rB[2];
    if (wm == 0) {
#pragma unroll
        for (int ni = 0; ni < 2; ++ni) {
            const int col = n0 + wn * 32 + ni * 16 + l16;
            const float bzv = bz[col], bhv = bh[col];
            float runA = 1.f, runB = 0.f;
#pragma unroll
            for (int mi = 0; mi < 4; ++mi) {
                float av[4], bv[4], pA = 1.f, pB = 0.f;
#pragma unroll
                for (int j = 0; j < 4; ++j) {
                    gate_transform(accz[mi][ni][j] + bzv, acch[mi][ni][j] + bhv, av[j], bv[j]);
                    pB = fmaf(av[j], pB, bv[j]); pA *= av[j];
                }
                float fA, fB, prA, prB;
                qscan(q, pA, pB, fA, fB, prA, prB);
                runB = fmaf(fA, runB, fB); runA *= fA;
            }
            rB[ni] = runB;
        }
    }
    __syncthreads();                   // all waves done reading As/Bs
    if (wm == 0 && q == 0) {
#pragma unroll
        for (int ni = 0; ni < 2; ++ni)
            carray[wn * 32 + ni * 16 + l16] = rB[ni];
    }
    __syncthreads();                   // carry visible
    // ---- live window (wm=1): scan with carry, stage rows into h0s ----
    if (wm == 1) {
#pragma unroll
        for (int ni = 0; ni < 2; ++ni) {
            const int colloc = wn * 32 + ni * 16 + l16;
            const int col = n0 + colloc;
            const float bzv = bz[col], bhv = bh[col];
            float H = carray[colloc];
#pragma unroll
            for (int mi = 0; mi < 4; ++mi) {
                float av[4], bv[4], pA = 1.f, pB = 0.f;
#pragma unroll
                for (int j = 0; j < 4; ++j) {
                    gate_transform(accz[mi][ni][j] + bzv, acch[mi][ni][j] + bhv, av[j], bv[j]);
                    pB = fmaf(av[j], pB, bv[j]); pA *= av[j];
                }
                float fA, fB, prA, prB;
                qscan(q, pA, pB, fA, fB, prA, prB);
                float Hl = fmaf(prA, H, prB);
                const int rloc = mi * 16 + q * 4;      // 0..63
#pragma unroll
                for (int j = 0; j < 4; ++j) {
                    Hl = fmaf(av[j], Hl, bv[j]);
                    h0s[(rloc + j) * 68 + colloc] = (__half)Hl;
                }
                H = fmaf(fA, H, fB);
            }
        }
    }
    __syncthreads();
    {   // coalesced writeout: 64 rows x 64 cols fp16
        const int row = tid >> 2, cpart = tid & 3;
        const __half* srcp = h0s + row * 68 + cpart * 16;
        __half* dstp = h0red + (size_t)(by * 64 + row) * 512 + n0 + cpart * 16;
        *(uint4*)dstp = *(const uint4*)srcp;
        *(uint4*)(dstp + 8) = *(const uint4*)(srcp + 8);
    }
}

// ---------------- k4: layer-1 MFMA + fused output GEMV ----------------------------
// Grid (4, 8): m-tile 128 rows = 2 batches (wm = batch parity), n-tile 128 cols.
// r16 loop (counted vmcnt(6), raw barriers, (256,2) clamp, unrolled, hoisted).
// Epilogue: per-batch 64-step composite B == h1[L-1]; partial dot with Wf,
// wave-reduce, atomicAdd into out[batch] (init'd to bf by k1s).
__global__ __launch_bounds__(256, 2) void k4_l1(
    const __half* __restrict__ h0red,
    const __half* __restrict__ Wtz, const __half* __restrict__ Wth,  // [512][512] fp16
    const float* __restrict__ bz, const float* __restrict__ bh,
    const float* __restrict__ Wf, float* __restrict__ out)
{
    __shared__ char smem4[2][24576];     // per buf: A 8KB (128x32) + B 16KB (256x32)
    const int tid = threadIdx.x;
    const int wave = tid >> 6, lane = tid & 63;
    const int q = lane >> 4, l16 = lane & 15;
    const int wm = wave >> 1, wn = wave & 1;

    const int bx = blockIdx.x, by = blockIdx.y;
    const int m0 = by * 128, n0 = bx * 128;

    const int r4 = lane >> 2, ch = lane & 3;

    const __half* aSrc[2]; int aDst[2];
#pragma unroll
    for (int i = 0; i < 2; ++i) {
        const int reg = wave * 2 + i;
        const int row = reg * 16 + r4;
        const int pc = ch ^ ((row >> 1) & 3);
        aSrc[i] = h0red + (size_t)(m0 + row) * 512 + pc * 8;
        aDst[i] = reg * 1024;
    }
    const __half* bSrc[4]; int bDst[4];
#pragma unroll
    for (int i = 0; i < 4; ++i) {
        const int reg = wave * 4 + i;
        const int row = reg * 16 + r4;
        const int pc = ch ^ ((row >> 1) & 3);
        bSrc[i] = ((row < 128) ? (Wtz + (size_t)(n0 + row) * 512)
                               : (Wth + (size_t)(n0 + row - 128) * 512)) + pc * 8;
        bDst[i] = 8192 + reg * 1024;
    }
    int aOff[4], bOff[4];
#pragma unroll
    for (int mi = 0; mi < 4; ++mi) {
        const int row = wm * 64 + mi * 16 + l16;
        aOff[mi] = row * 64 + ((q ^ ((row >> 1) & 3)) << 4);
    }
#pragma unroll
    for (int ni = 0; ni < 4; ++ni) {
        const int rn = wn * 64 + ni * 16 + l16;
        bOff[ni] = 8192 + rn * 64 + ((q ^ ((rn >> 1) & 3)) << 4);
    }

    f32x4 accz[4][4], acch[4][4];
#pragma unroll
    for (int mi = 0; mi < 4; ++mi)
#pragma unroll
        for (int ni = 0; ni < 4; ++ni) {
            accz[mi][ni] = (f32x4){0.f, 0.f, 0.f, 0.f};
            acch[mi][ni] = (f32x4){0.f, 0.f, 0.f, 0.f};
        }

    auto stage = [&](int c, int t) {
#pragma unroll
        for (int i = 0; i < 2; ++i)
            gload16(aSrc[i] + t * 32, smem4[c] + aDst[i]);
#pragma unroll
        for (int i = 0; i < 4; ++i)
            gload16(bSrc[i] + t * 32, smem4[c] + bDst[i]);
    };
    auto compute = [&](int c) {
        half8 af[4];
#pragma unroll
        for (int mi = 0; mi < 4; ++mi)
            af[mi] = *(const half8*)(smem4[c] + aOff[mi]);
        __builtin_amdgcn_s_setprio(1);
#pragma unroll
        for (int ni = 0; ni < 4; ++ni) {
            half8 bzf = *(const half8*)(smem4[c] + bOff[ni]);
            half8 bhf = *(const half8*)(smem4[c] + 8192 + bOff[ni]);
#pragma unroll
            for (int mi = 0; mi < 4; ++mi) {
                accz[mi][ni] = __builtin_amdgcn_mfma_f32_16x16x32_f16(af[mi], bzf, accz[mi][ni], 0, 0, 0);
                acch[mi][ni] = __builtin_amdgcn_mfma_f32_16x16x32_f16(af[mi], bhf, acch[mi][ni], 0, 0, 0);
            }
        }
        __builtin_amdgcn_s_setprio(0);
    };

    stage(0, 0);
#pragma unroll
    for (int t = 0; t < 15; ++t) {
        const int c = t & 1;
        stage(c ^ 1, t + 1);
        asm volatile("s_waitcnt vmcnt(6)" ::: "memory");
        __builtin_amdgcn_s_barrier();
        compute(c);
        __builtin_amdgcn_s_barrier();
    }
    asm volatile("s_waitcnt vmcnt(0)" ::: "memory");
    __builtin_amdgcn_s_barrier();
    compute(1);

    // epilogue: 64-step composite per batch (wm) -> h1[L-1]; fused GEMV with Wf
    const int batch = by * 2 + wm;
    float part = 0.f;
#pragma unroll
    for (int ni = 0; ni < 4; ++ni) {
        const int col = n0 + wn * 64 + ni * 16 + l16;
        const float bzv = bz[col], bhv = bh[col];
        float fullA = 1.f, fullB = 0.f;
#pragma unroll
        for (int mi = 0; mi < 4; ++mi) {
            float pA = 1.f, pB = 0.f;
#pragma unroll
            for (int j = 0; j < 4; ++j) {
                float a, b;
                gate_transform(accz[mi][ni][j] + bzv, acch[mi][ni][j] + bhv, a, b);
                pB = fmaf(a, pB, b); pA *= a;
            }
            float fA, fB, prA, prB;
            qscan(q, pA, pB, fA, fB, prA, prB);
            fullB = fmaf(fA, fullB, fB); fullA *= fA;
        }
        if (q == 0) part = fmaf(fullB, Wf[col], part);
    }
#pragma unroll
    for (int off = 32; off; off >>= 1) part += __shfl_down(part, off, 64);
    if (lane == 0) atomicAdd(&out[batch], part);
}

extern "C" void kernel_launch(void* const* d_in, const int* in_sizes, int n_in,
                              void* d_out, int out_size, void* d_ws, size_t ws_size,
                              hipStream_t stream)
{
    const float* x   = (const float*)d_in[0];
    const float* Wz0 = (const float*)d_in[1];
    const float* bz0 = (const float*)d_in[2];
    const float* Wh0 = (const float*)d_in[3];
    const float* bh0 = (const float*)d_in[4];
    const float* Wz1 = (const float*)d_in[5];
    const float* bz1 = (const float*)d_in[6];
    const float* Wh1 = (const float*)d_in[7];
    const float* bh1 = (const float*)d_in[8];
    const float* Wf  = (const float*)d_in[9];
    const float* bf  = (const float*)d_in[10];
    float* out = (float*)d_out;

    // workspace (~2 MiB)
    char* ws = (char*)d_ws;
    __half* h0red = (__half*)ws;                           // 1 MiB: [1024][512]
    __half* Wtz1  = (__half*)(ws + (1024 << 10));          // 512 KiB
    __half* Wth1  = Wtz1 + 262144;                         // 512 KiB

    k1s<<<dim3(8, 16), 256, 0, stream>>>(x, Wz0, Wh0, Wz1, Wh1, bz0, bh0, bf,
                                         Wtz1, Wth1, h0red, out);
    k4_l1<<<dim3(4, 8), 256, 0, stream>>>(h0red, Wtz1, Wth1, bz1, bh1, Wf, out);
}